// Round 11
// baseline (227.496 us; speedup 1.0000x reference)
//
#include <hip/hip_runtime.h>
#include <stdint.h>

// ===========================================================================
// AnchorDataGenerator (Faster R-CNN anchor target layer), MI355X / gfx950
// Round 14: HISTOGRAM ELIMINATED. k_one was invariant at ~44us across all
// spin/counter restructurings (R6=R13=44.3) -> the common core is the
// ~400K-atomic global histogram phase (IF atomic throughput ~20-30us).
// Replace hist+select+boundary-bin+fixup with exact threshold top-K:
//   B: per-block class counts (2 atomics/block, fanned) -> completer:
//      totals -> Kf,Kb, per-class threshold T (expected ~512 pushes)
//   D: blocks push keys mant<T to 32 hash-fanned lists; completer gathers
//      (parallel, R13-proven), checks count in [K,1024] (retry loop with
//      adjusted T for absolute exactness; P(retry)~e^-85), ranks C~512 in
//      LDS, publishes the EXACT K-th smallest key per class.
//   Emit: kept <=> key <= B_key (keys unique -> exact, same kept set as
//      validated hist pipeline) -> plain stores, no fixup, sole writers.
// Kept verbatim: compute phase (analytic gmax, IoU, labels/adj), tree
// arrival barriers, fanned wake flags, memset+worker 2-dispatch, relaxed
// agent atomics only, vmcnt(0) before arrivals, parallel AG_LOAD gathers.
// ===========================================================================

#define NUM_A 9
#define HW 65536
#define N_ANCH 589824
#define NG 64
#define CAPK 128u

#define LAB_BG 0u
#define LAB_FG 1u
#define LAB_IGN 2u

#define NBLK 576

#define NGRP 32
#define GCAP 256u
#define R_MAX 8
#define TARGETC 512u
#define TFULL (1u << 23)
#define CLIMIT 1024u
#define GATHER_CAP 2048u

// workspace layout (u32 words)
#define OFF_CNTF  0                     // 32 x stride16 per-group fg counts
#define OFF_CNTB  512                   // 32 x stride16 bg counts
#define OFF_SUBB  1024                  // 32 x stride16 barrier-B subs
#define OFF_ROOTB 1536                  // root (pad 16)
#define OFF_SELB  1552                  // {Tf,Tb,Kf,Kb,totF,totB} (pad 16)
#define OFF_CFLGB 1568                  // 32 x stride16 wake-B flags
#define OFF_RND   2080                  // per-round blocks
#define RSTRIDE   2080
#define R_SUBD    0                     // 32 x 16
#define R_ROOTD   512                   // 16
#define R_DCMD    528                   // 16: {st,mF,bkFlo,bkFhi,mB,bkBlo,bkBhi,TfN,TbN}
#define R_CFLGD   544                   // 32 x 16
#define R_PCNTF   1056                  // 32 x 16 push counters fg
#define R_PCNTB   1568                  // 32 x 16 push counters bg
#define CTRL_WORDS (OFF_RND + R_MAX * RSTRIDE)   // 18720 words = 74.9 KB
#define OFF_LISTF CTRL_WORDS            // 18720 (byte 74880, 8B aligned)
#define OFF_LISTB (OFF_LISTF + 2 * NGRP * GCAP)  // 35104; end 51488 (~206KB)

#define MAGIC_C 0x5CA1AB1Eu

__constant__ float BA[NUM_A][4] = {
  { -84.f,  -40.f,  99.f,  55.f}, {-176.f,  -88.f, 191.f, 103.f},
  {-360.f, -184.f, 375.f, 199.f}, { -56.f,  -56.f,  71.f,  71.f},
  {-120.f, -120.f, 135.f, 135.f}, {-248.f, -248.f, 263.f, 263.f},
  { -36.f,  -80.f,  51.f,  95.f}, { -80.f, -168.f,  95.f, 183.f},
  {-168.f, -344.f, 183.f, 359.f}};

__host__ __device__ static inline void tf2x32(uint32_t k0, uint32_t k1,
                                              uint32_t x0, uint32_t x1,
                                              uint32_t* o0, uint32_t* o1) {
  const uint32_t ks2 = k0 ^ k1 ^ 0x1BD11BDAu;
#define TF_R(r) { x0 += x1; x1 = (x1 << (r)) | (x1 >> (32 - (r))); x1 ^= x0; }
  x0 += k0; x1 += k1;
  TF_R(13) TF_R(15) TF_R(26) TF_R(6)
  x0 += k1;  x1 += ks2 + 1u;
  TF_R(17) TF_R(29) TF_R(16) TF_R(24)
  x0 += ks2; x1 += k0 + 2u;
  TF_R(13) TF_R(15) TF_R(26) TF_R(6)
  x0 += k0;  x1 += k1 + 3u;
  TF_R(17) TF_R(29) TF_R(16) TF_R(24)
  x0 += k1;  x1 += ks2 + 4u;
  TF_R(13) TF_R(15) TF_R(26) TF_R(6)
  x0 += ks2; x1 += k0 + 5u;
#undef TF_R
  *o0 = x0; *o1 = x1;
}

__device__ static inline uint32_t mant_of(uint32_t k0, uint32_t k1, uint32_t n) {
  uint32_t o0, o1;
  tf2x32(k0, k1, 0u, n, &o0, &o1);
  return (o0 ^ o1) >> 9;                 // 23-bit mantissa
}

// Max of fl(iw) over valid integer shifts [lo,hi] for one axis (concave,
// unimodal; max at clamped floor/ceil of continuous argmax endpoints).
__device__ static inline float axis_best(float blo, float bhi, float glo,
                                         float ghi, int lo, int hi) {
  #pragma clang fp contract(off)
  float t1 = (ghi - bhi) * 0.0625f;
  float t2 = (glo - blo) * 0.0625f;
  float tmin = fminf(t1, t2), tmax = fmaxf(t1, t2);
  int c1 = (int)floorf(tmin), c2 = (int)ceilf(tmax);
  int cand0 = lo, cand1 = hi;
  int cand2 = min(max(c1,     lo), hi);
  int cand3 = min(max(c1 + 1, lo), hi);
  int cand4 = min(max(c2 - 1, lo), hi);
  int cand5 = min(max(c2,     lo), hi);
  float best = -3.0e38f;
  int cands[6] = {cand0, cand1, cand2, cand3, cand4, cand5};
  #pragma unroll
  for (int i = 0; i < 6; i++) {
    float s = (float)(cands[i] << 4);
    float v = fminf(bhi + s, ghi) - fmaxf(blo + s, glo) + 1.0f;
    best = fmaxf(best, v);
  }
  return best;
}

#define AG_LOAD(p)      __hip_atomic_load((p), __ATOMIC_RELAXED, __HIP_MEMORY_SCOPE_AGENT)
#define AG_STORE(p, v)  __hip_atomic_store((p), (v), __ATOMIC_RELAXED, __HIP_MEMORY_SCOPE_AGENT)

__global__ __launch_bounds__(256) void k_one(const float* __restrict__ gt,
                                             const int* __restrict__ imw_p,
                                             const int* __restrict__ imh_p,
                                             float* __restrict__ out_lab,
                                             float* __restrict__ out_adj,
                                             float* __restrict__ out_wts,
                                             uint32_t* __restrict__ ws,
                                             uint32_t kf0, uint32_t kf1,
                                             uint32_t kb0, uint32_t kb1) {
  #pragma clang fp contract(off)
  __shared__ uint64_t scB[GATHER_CAP];       // 16 KB gather/rank buffer
  __shared__ float sg0[NG], sg1[NG], sg2[NG], sg3[NG], sga[NG], sgm[NG];
  __shared__ uint32_t sgmU[NG];
  __shared__ unsigned long long sMask[4];
  __shared__ int sAnyZero, sLastB, sLastD, sOv;
  __shared__ uint32_t sSel[12];
  __shared__ uint32_t sCnt[NGRP], sBase[NGRP], sTot, sBkLo, sBkHi;
  __shared__ uint32_t sCF, sCB;
  int tid = threadIdx.x;
  int b = blockIdx.x;
  int a = b >> 6, hb = (b & 63) << 2;        // anchor type, rows hb..hb+3

  if (tid == 0) { sAnyZero = 0; sCF = 0u; sCB = 0u; }
  if (tid < NG) {
    const float4 g4 = ((const float4*)gt)[tid];
    sg0[tid] = g4.x; sg1[tid] = g4.y; sg2[tid] = g4.z; sg3[tid] = g4.w;
    float gw = g4.z - g4.x + 1.0f, gh = g4.w - g4.y + 1.0f;
    sga[tid] = (gw > 0.0f && gh > 0.0f) ? gw * gh : 0.0f;
    sgmU[tid] = 0u;
  }
  __syncthreads();   // S1

  // ---- local analytic gmax (LDS atomicMax on float bits; IoU >= 0) ----
  {
    int imwi = imw_p[0], imhi = imh_p[0];
    for (int p = tid; p < NG * NUM_A; p += 256) {
      int g = p / NUM_A, q = p - g * NUM_A;
      float b0 = BA[q][0], b1 = BA[q][1], b2 = BA[q][2], b3 = BA[q][3];
      int ib0 = (int)b0, ib1 = (int)b1, ib2 = (int)b2, ib3 = (int)b3;
      int wlo = max(0, (-ib0 + 15) >> 4);
      int whi = min(255, (imwi - ib2 - 1) >> 4);
      int hlo = max(0, (-ib1 + 15) >> 4);
      int hhi = min(255, (imhi - ib3 - 1) >> 4);
      if (wlo > whi || hlo > hhi) continue;
      float iwb = axis_best(b0, b2, sg0[g], sg2[g], wlo, whi);
      float ihb = axis_best(b1, b3, sg1[g], sg3[g], hlo, hhi);
      float aw = b2 - b0 + 1.0f, ah = b3 - b1 + 1.0f;
      float aarea = aw * ah;
      float inter = (iwb > 0.0f && ihb > 0.0f) ? iwb * ihb : 0.0f;
      float den = aarea + sga[g] - inter;
      float o = inter / den;
      atomicMax(&sgmU[g], __float_as_uint(o));
    }
  }

  // per-wave y-mask
  {
    int wv = tid >> 6, g = tid & 63;
    float sy = (float)((hb + wv) << 4);
    float ihp = fminf(BA[a][3] + sy, sg3[g]) - fmaxf(BA[a][1] + sy, sg1[g]) + 1.0f;
    unsigned long long mk = __ballot(ihp > 0.0f);
    if (g == 0) sMask[wv] = mk;
  }
  __syncthreads();   // S2
  if (tid < NG) {
    uint32_t mm = sgmU[tid];
    sgm[tid] = __uint_as_float(mm);
    if (mm == 0u) atomicOr(&sAnyZero, 1);
  }
  __syncthreads();   // S3

  float BA0 = BA[a][0], BA1 = BA[a][1], BA2 = BA[a][2], BA3 = BA[a][3];
  float imw = (float)imw_p[0], imh = (float)imh_p[0];
  int w = tid;
  float sx = (float)(w << 4);
  float A0 = BA0 + sx, A2 = BA2 + sx;
  float aw = A2 - A0 + 1.0f;
  float A1v[4], A3v[4];
  #pragma unroll
  for (int r = 0; r < 4; r++) {
    float sy = (float)((hb + r) << 4);
    A1v[r] = BA1 + sy; A3v[r] = BA3 + sy;
  }
  float ah = A3v[0] - A1v[0] + 1.0f;
  float aarea = aw * ah;
  bool xv = (A0 >= 0.0f) && (A2 < imw);

  unsigned long long mk0 = sMask[0], mk1 = sMask[1],
                     mk2 = sMask[2], mk3 = sMask[3];
  unsigned long long uni = mk0 | mk1 | mk2 | mk3;
  float amaxv[4] = {0.f, 0.f, 0.f, 0.f};
  int bgv[4] = {0, 0, 0, 0};
  uint32_t afv = 0u;
  while (uni) {
    int g = __ffsll(uni) - 1;
    uni &= uni - 1;
    float iw = fminf(A2, sg2[g]) - fmaxf(A0, sg0[g]) + 1.0f;
    if (!__any(iw > 0.0f)) continue;
    if (iw > 0.0f) {
      float base = aarea + sga[g];
      float gy1 = sg1[g], gy2 = sg3[g], gm = sgm[g];
#define DO_ROW(r, mk)                                                     \
      if ((mk >> g) & 1ull) {                                             \
        float ih = fminf(A3v[r], gy2) - fmaxf(A1v[r], gy1) + 1.0f;        \
        float inter = iw * ih;                                            \
        float o = inter / (base - inter);                                 \
        if (o > amaxv[r]) { amaxv[r] = o; bgv[r] = g; }                   \
        if (o == gm) afv |= (1u << r);                                    \
      }
      DO_ROW(0, mk0) DO_ROW(1, mk1) DO_ROW(2, mk2) DO_ROW(3, mk3)
#undef DO_ROW
    }
  }

  bool anyZ = (sAnyZero != 0);
  uint32_t lm[4];
  uint32_t cfLoc = 0, cbLoc = 0;
  #pragma unroll
  for (int r = 0; r < 4; r++) {
    int hw = (hb + r) * 256 + w;
    bool valid = xv && (A1v[r] >= 0.0f) && (A3v[r] < imh);
    float amax = amaxv[r];
    bool anyfg = (((afv >> r) & 1u) || anyZ) && valid;
    uint32_t lab;
    if (!valid)                       lab = LAB_IGN;
    else if (anyfg || amax >= 0.7f)   lab = LAB_FG;
    else if (amax < 0.3f)             lab = LAB_BG;
    else                              lab = LAB_IGN;

    float adj0 = 0.f, adj1 = 0.f, adj2 = 0.f, adj3 = 0.f;
    if (valid) {
      int bg = bgv[r];
      float G0 = sg0[bg], G1 = sg1[bg], G2 = sg2[bg], G3 = sg3[bg];
      float ax = (A2 + A0) * 0.5f, ay = (A3v[r] + A1v[r]) * 0.5f;
      float gwm = G2 - G0 + 1.0f, ghm = G3 - G1 + 1.0f;
      float gx = (G2 + G0) * 0.5f, gy = (G3 + G1) * 0.5f;
      adj0 = (gx - ax) / aw;
      adj1 = (gy - ay) / ah;
      adj2 = logf(gwm / aw);
      adj3 = logf(ghm / ah);
    }
    int c4 = a * 4;
    out_adj[(c4 + 0) * HW + hw] = adj0;
    out_adj[(c4 + 1) * HW + hw] = adj1;
    out_adj[(c4 + 2) * HW + hw] = adj2;
    out_adj[(c4 + 3) * HW + hw] = adj3;

    uint32_t m = 0u;
    uint32_t n = (uint32_t)(hw * 9 + a);
    if (lab != LAB_IGN) {
      uint32_t kk0 = (lab == LAB_FG) ? kf0 : kb0;
      uint32_t kk1 = (lab == LAB_FG) ? kf1 : kb1;
      m = mant_of(kk0, kk1, n);
      if (lab == LAB_FG) cfLoc++; else cbLoc++;
    }
    lm[r] = (lab << 24) | m;                 // stays in registers
  }
  if (cfLoc) atomicAdd(&sCF, cfLoc);
  if (cbLoc) atomicAdd(&sCB, cbLoc);
  __syncthreads();

  // ---- barrier B: publish per-block counts, tree arrival ----
  if (tid == 0) {
    if (sCF) atomicAdd(&ws[OFF_CNTF + (b & 31) * 16], sCF);
    if (sCB) atomicAdd(&ws[OFF_CNTB + (b & 31) * 16], sCB);
    asm volatile("s_waitcnt vmcnt(0)" ::: "memory");
    int last = 0;
    uint32_t v = atomicAdd(&ws[OFF_SUBB + (b & 31) * 16], 1u);
    if (v == 17u) {
      uint32_t q = atomicAdd(&ws[OFF_ROOTB], 1u);
      if (q == 31u) last = 1;
    }
    sLastB = last;
  }
  __syncthreads();
  if (sLastB) {
    // completer B: totals -> K, threshold T per class; publish SELB
    if (tid < 32)       sCnt[tid] = AG_LOAD(&ws[OFF_CNTF + tid * 16]);
    else if (tid < 64)  sBase[tid - 32] = AG_LOAD(&ws[OFF_CNTB + (tid - 32) * 16]);
    __syncthreads();
    if (tid == 0) {
      uint32_t tf = 0, tb = 0;
      for (int i = 0; i < 32; i++) { tf += sCnt[i]; tb += sBase[i]; }
      uint32_t Kf_ = tf < CAPK ? tf : CAPK;
      uint32_t Kb_ = tb < CAPK ? tb : CAPK;
      uint32_t Tf_ = (tf <= TARGETC) ? TFULL
                   : (uint32_t)(((unsigned long long)TARGETC << 23) / tf);
      uint32_t Tb_ = (tb <= TARGETC) ? TFULL
                   : (uint32_t)(((unsigned long long)TARGETC << 23) / tb);
      if (Tf_ == 0u) Tf_ = 1u;
      if (Tb_ == 0u) Tb_ = 1u;
      AG_STORE(&ws[OFF_SELB + 0], Tf_); AG_STORE(&ws[OFF_SELB + 1], Tb_);
      AG_STORE(&ws[OFF_SELB + 2], Kf_); AG_STORE(&ws[OFF_SELB + 3], Kb_);
      AG_STORE(&ws[OFF_SELB + 4], tf);  AG_STORE(&ws[OFF_SELB + 5], tb);
    }
    asm volatile("s_waitcnt vmcnt(0)" ::: "memory");
    __syncthreads();
    if (tid < 32) AG_STORE(&ws[OFF_CFLGB + tid * 16], MAGIC_C);
  }

  // ---- wake B (fanned) ----
  if (tid == 0) {
    while (AG_LOAD(&ws[OFF_CFLGB + (b & 31) * 16]) != MAGIC_C)
      __builtin_amdgcn_s_sleep(2);
  }
  __syncthreads();
  if (tid < 6) sSel[tid] = AG_LOAD(&ws[OFF_SELB + tid]);
  __syncthreads();
  uint32_t Tc[2] = {sSel[0], sSel[1]};       // cls 0 = FG, 1 = BG
  uint32_t Kf = sSel[2], Kb = sSel[3], totF = sSel[4], totB = sSel[5];
  float inv = 1.0f / (float)(Kf + Kb);       // 1/num_ni (unused if 0 kept)

  // ---- round loop: push keys < T, completer ranks exact K-th key ----
  uint32_t modeF = 0u, modeB = 0u;           // 0 NONE, 1 ALL, 2 THRESH
  uint64_t bkF = 0ull, bkB = 0ull;
  bool doneSel = false;
  for (int rnd = 0; rnd < R_MAX && !doneSel; rnd++) {
    uint32_t base = OFF_RND + (uint32_t)rnd * RSTRIDE;
    // push
    #pragma unroll
    for (int r = 0; r < 4; r++) {
      uint32_t lab = lm[r] >> 24;
      if (lab == LAB_IGN) continue;
      uint32_t m = lm[r] & 0x7FFFFFu;
      int cls = (lab == LAB_FG) ? 0 : 1;
      if (m < Tc[cls]) {
        int hw = (hb + r) * 256 + w;
        uint32_t n = (uint32_t)(hw * 9 + a);
        uint32_t grp = (n * 2654435761u) >> 27;      // uniform hash group
        uint32_t idx = atomicAdd(
            &ws[base + (cls ? R_PCNTB : R_PCNTF) + grp * 16], 1u);
        if (idx < GCAP) {
          uint64_t* lst =
              (uint64_t*)(ws + (cls ? OFF_LISTB : OFF_LISTF)) + grp * GCAP;
          AG_STORE(&lst[idx], ((uint64_t)m << 20) | (uint64_t)n);
        }
      }
    }
    asm volatile("s_waitcnt vmcnt(0)" ::: "memory");
    __syncthreads();
    // arrival D_rnd
    if (tid == 0) {
      int last = 0;
      uint32_t v = atomicAdd(&ws[base + R_SUBD + (b & 31) * 16], 1u);
      if (v == 17u) {
        uint32_t q = atomicAdd(&ws[base + R_ROOTD], 1u);
        if (q == 31u) last = 1;
      }
      sLastD = last;
    }
    __syncthreads();
    if (sLastD) {
      uint32_t modes[2]; uint64_t bks[2]; int oks[2];
      uint32_t Cs[2]; int ovs[2];
      for (int cls = 0; cls < 2; cls++) {
        uint32_t Kc = cls ? Kb : Kf;
        uint32_t totc = cls ? totB : totF;
        if (tid < 32)
          sCnt[tid] = AG_LOAD(&ws[base + (cls ? R_PCNTB : R_PCNTF) + tid * 16]);
        __syncthreads();
        if (tid == 0) {
          uint32_t acc = 0; int ov = 0;
          for (int g2 = 0; g2 < NGRP; g2++) {
            uint32_t c2 = sCnt[g2];
            if (c2 > GCAP) { ov = 1; c2 = GCAP; }
            sBase[g2] = acc; acc += c2;
          }
          sTot = acc; sOv = ov;
        }
        __syncthreads();
        uint32_t C = sTot; int ov = sOv;
        uint32_t mode = 0u; uint64_t bk = 0ull; int ok = 1;
        if (Kc == 0u) { ok = 1; mode = 0u; }
        else if (totc <= CAPK) { ok = (!ov && C == totc); mode = 1u; }
        else {
          ok = (!ov && C >= Kc && C <= CLIMIT &&
                (totc > TARGETC || C == totc));
          mode = 2u;
        }
        if (ok && mode == 2u) {
          const uint64_t* lst0 =
              (const uint64_t*)(ws + (cls ? OFF_LISTB : OFF_LISTF));
          for (uint32_t idx = tid; idx < NGRP * GCAP; idx += 256) {
            uint32_t g2 = idx >> 8, i = idx & 255u;     // GCAP = 256
            if (i < sCnt[g2]) {
              uint32_t dst = sBase[g2] + i;
              if (dst < GATHER_CAP)
                scB[dst] = AG_LOAD(&lst0[g2 * GCAP + i]);
            }
          }
          __syncthreads();
          for (uint32_t i = tid; i < C; i += 256) {
            uint64_t k = scB[i];
            uint32_t rr = 0;
            for (uint32_t j = 0; j < C; j++) rr += (scB[j] < k) ? 1u : 0u;
            if (rr == Kc - 1u) {                 // exact K-th smallest
              sBkLo = (uint32_t)k; sBkHi = (uint32_t)(k >> 32);
            }
          }
          __syncthreads();
          bk = ((uint64_t)sBkHi << 32) | (uint64_t)sBkLo;
        }
        modes[cls] = mode; bks[cls] = bk; oks[cls] = ok;
        Cs[cls] = C; ovs[cls] = ov;
        __syncthreads();
      }
      uint32_t st = (oks[0] && oks[1]) ? 1u : 2u;
      uint32_t TN[2];
      for (int cls = 0; cls < 2; cls++) {
        uint32_t t = Tc[cls];
        if (!oks[cls]) {
          if (ovs[cls] || Cs[cls] > CLIMIT) t = (t > 1u) ? (t >> 1) : 1u;
          else { t = (t >= (TFULL >> 2)) ? TFULL : (t << 2); }
        }
        TN[cls] = t;
      }
      if (tid == 0) {
        AG_STORE(&ws[base + R_DCMD + 0], st);
        AG_STORE(&ws[base + R_DCMD + 1], modes[0]);
        AG_STORE(&ws[base + R_DCMD + 2], (uint32_t)bks[0]);
        AG_STORE(&ws[base + R_DCMD + 3], (uint32_t)(bks[0] >> 32));
        AG_STORE(&ws[base + R_DCMD + 4], modes[1]);
        AG_STORE(&ws[base + R_DCMD + 5], (uint32_t)bks[1]);
        AG_STORE(&ws[base + R_DCMD + 6], (uint32_t)(bks[1] >> 32));
        AG_STORE(&ws[base + R_DCMD + 7], TN[0]);
        AG_STORE(&ws[base + R_DCMD + 8], TN[1]);
      }
      asm volatile("s_waitcnt vmcnt(0)" ::: "memory");
      __syncthreads();
      if (tid < 32) AG_STORE(&ws[base + R_CFLGD + tid * 16], MAGIC_C);
    }
    // wake D_rnd (fanned)
    if (tid == 0) {
      while (AG_LOAD(&ws[base + R_CFLGD + (b & 31) * 16]) != MAGIC_C)
        __builtin_amdgcn_s_sleep(2);
    }
    __syncthreads();
    if (tid < 9) sSel[tid] = AG_LOAD(&ws[base + R_DCMD + tid]);
    __syncthreads();
    if (sSel[0] == 1u) {
      modeF = sSel[1]; bkF = ((uint64_t)sSel[3] << 32) | (uint64_t)sSel[2];
      modeB = sSel[4]; bkB = ((uint64_t)sSel[6] << 32) | (uint64_t)sSel[5];
      doneSel = true;
    } else {
      Tc[0] = sSel[7]; Tc[1] = sSel[8];
    }
    __syncthreads();
  }

  // ---- emit: kept <=> key <= K-th smallest key (exact, sole writers) ----
  #pragma unroll
  for (int r = 0; r < 4; r++) {
    int hw = (hb + r) * 256 + w;
    uint32_t lab = lm[r] >> 24;
    uint32_t m = lm[r] & 0x7FFFFFu;
    uint32_t n = (uint32_t)(hw * 9 + a);
    uint64_t key = ((uint64_t)m << 20) | (uint64_t)n;
    float outv = 2.0f, wv = 0.0f;
    if (lab == LAB_FG) {
      bool kept = (modeF == 1u) || (modeF == 2u && key <= bkF);
      if (kept) { outv = 1.0f; wv = inv; }
    } else if (lab == LAB_BG) {
      bool kept = (modeB == 1u) || (modeB == 2u && key <= bkB);
      if (kept) outv = 0.0f;
    }
    out_lab[a * HW + hw] = outv;
    int c4 = a * 4;
    out_wts[(c4 + 0) * HW + hw] = wv;
    out_wts[(c4 + 1) * HW + hw] = wv;
    out_wts[(c4 + 2) * HW + hw] = wv;
    out_wts[(c4 + 3) * HW + hw] = wv;
  }
}

extern "C" void kernel_launch(void* const* d_in, const int* in_sizes, int n_in,
                              void* d_out, int out_size, void* d_ws,
                              size_t ws_size, hipStream_t stream) {
  const float* gt  = (const float*)d_in[1];
  const int*   imw = (const int*)d_in[2];
  const int*   imh = (const int*)d_in[3];
  float* out      = (float*)d_out;
  float* out_lab  = out;                   // 589824
  float* out_adj  = out + N_ANCH;          // 4*589824
  float* out_wts  = out + 5 * N_ANCH;      // 4*589824
  uint32_t* ws = (uint32_t*)d_ws;          // ~206 KB used

  uint32_t kf0, kf1, kb0, kb1;
  tf2x32(0u, 42u, 0u, 0u, &kf0, &kf1);
  tf2x32(0u, 42u, 0u, 1u, &kb0, &kb1);

  // Stream-ordered zero of ctrl region (counts, barriers, flags, per-round
  // push counters): every run starts clean (R10 re-poison lesson).
  hipMemsetAsync(ws, 0, CTRL_WORDS * sizeof(uint32_t), stream);
  // Residency by capacity: 576 blocks, ~18KB LDS -> 8 blocks/CU (2048
  // slots) >> 576; sole kernel on the stream -> all co-resident.
  hipLaunchKernelGGL(k_one, dim3(NBLK), dim3(256), 0, stream, gt, imw, imh,
                     out_lab, out_adj, out_wts, ws, kf0, kf1, kb0, kb1);
}

// Round 12
// 225.090 us; speedup vs baseline: 1.0107x; 1.0107x over previous
//
#include <hip/hip_runtime.h>
#include <stdint.h>

// ===========================================================================
// AnchorDataGenerator (Faster R-CNN anchor target layer), MI355X / gfx950
// Round 15 = R14 (hist-free threshold top-K, absmax 0) + wake-transport fix.
// R14 failure mode (170us, occ 26%, VALUBusy 5%): 576 blocks arriving
// SIMULTANEOUSLY at the wake points poll 32 shared flags continuously;
// 18 pollers/addr x 0.46us period x ~28ns same-address service = >100%
// utilization -> flag queues saturate, completer's stores queue behind.
// Fix: PER-BLOCK wake flags (576 x 64B; 1 poller/address -> no queueing);
// completer broadcasts with 256 threads in parallel (~2us). Wake-D flags
// carry round number (rnd+1), memset-cleared per run.
// Everything else verbatim from R14:
//   compute (analytic gmax, IoU, labels/adj) -> per-block class counts ->
//   barrier B (tree) -> completer: totals, K, threshold T -> wake-B ->
//   push keys m<T to 32 hash-fanned lists -> barrier D (tree) -> completer:
//   parallel gather, exact K-th-smallest key (bounded retry) -> wake-D ->
//   emit: kept <=> key <= bk (exact; sole writers; plain stores).
// ===========================================================================

#define NUM_A 9
#define HW 65536
#define N_ANCH 589824
#define NG 64
#define CAPK 128u

#define LAB_BG 0u
#define LAB_FG 1u
#define LAB_IGN 2u

#define NBLK 576

#define NGRP 32
#define GCAP 256u
#define R_MAX 8
#define TARGETC 512u
#define TFULL (1u << 23)
#define CLIMIT 1024u
#define GATHER_CAP 2048u

// workspace layout (u32 words)
#define OFF_CNTF  0                      // 32 x stride16 per-group fg counts
#define OFF_CNTB  512                    // 32 x stride16 bg counts
#define OFF_SUBB  1024                   // 32 x stride16 barrier-B subs
#define OFF_ROOTB 1536                   // root (pad 16)
#define OFF_SELB  1552                   // {Tf,Tb,Kf,Kb,totF,totB} (pad 16)
#define OFF_WAKEB 1568                   // 576 x stride16 per-BLOCK flags
#define OFF_RND   (OFF_WAKEB + NBLK*16)  // 10784: per-round blocks
#define RSTRIDE   1568
#define R_SUBD    0                      // 32 x 16
#define R_ROOTD   512                    // 16
#define R_DCMD    528                    // 16: {st,mF,bkFlo,bkFhi,mB,bkBlo,bkBhi,TfN,TbN}
#define R_PCNTF   544                    // 32 x 16 push counters fg
#define R_PCNTB   1056                   // 32 x 16 push counters bg
#define OFF_WAKED (OFF_RND + R_MAX*RSTRIDE)  // 23328: 576 x 16, value rnd+1
#define CTRL_WORDS (OFF_WAKED + NBLK*16)     // 32544 words = 130 KB memset
#define OFF_LISTF CTRL_WORDS             // 32544 (byte 130176, 8B aligned)
#define OFF_LISTB (OFF_LISTF + 2*NGRP*GCAP)  // 48928; end 65312 (~261 KB)

__constant__ float BA[NUM_A][4] = {
  { -84.f,  -40.f,  99.f,  55.f}, {-176.f,  -88.f, 191.f, 103.f},
  {-360.f, -184.f, 375.f, 199.f}, { -56.f,  -56.f,  71.f,  71.f},
  {-120.f, -120.f, 135.f, 135.f}, {-248.f, -248.f, 263.f, 263.f},
  { -36.f,  -80.f,  51.f,  95.f}, { -80.f, -168.f,  95.f, 183.f},
  {-168.f, -344.f, 183.f, 359.f}};

__host__ __device__ static inline void tf2x32(uint32_t k0, uint32_t k1,
                                              uint32_t x0, uint32_t x1,
                                              uint32_t* o0, uint32_t* o1) {
  const uint32_t ks2 = k0 ^ k1 ^ 0x1BD11BDAu;
#define TF_R(r) { x0 += x1; x1 = (x1 << (r)) | (x1 >> (32 - (r))); x1 ^= x0; }
  x0 += k0; x1 += k1;
  TF_R(13) TF_R(15) TF_R(26) TF_R(6)
  x0 += k1;  x1 += ks2 + 1u;
  TF_R(17) TF_R(29) TF_R(16) TF_R(24)
  x0 += ks2; x1 += k0 + 2u;
  TF_R(13) TF_R(15) TF_R(26) TF_R(6)
  x0 += k0;  x1 += k1 + 3u;
  TF_R(17) TF_R(29) TF_R(16) TF_R(24)
  x0 += k1;  x1 += ks2 + 4u;
  TF_R(13) TF_R(15) TF_R(26) TF_R(6)
  x0 += ks2; x1 += k0 + 5u;
#undef TF_R
  *o0 = x0; *o1 = x1;
}

__device__ static inline uint32_t mant_of(uint32_t k0, uint32_t k1, uint32_t n) {
  uint32_t o0, o1;
  tf2x32(k0, k1, 0u, n, &o0, &o1);
  return (o0 ^ o1) >> 9;                 // 23-bit mantissa
}

// Max of fl(iw) over valid integer shifts [lo,hi] for one axis (concave,
// unimodal; max at clamped floor/ceil of continuous argmax endpoints).
__device__ static inline float axis_best(float blo, float bhi, float glo,
                                         float ghi, int lo, int hi) {
  #pragma clang fp contract(off)
  float t1 = (ghi - bhi) * 0.0625f;
  float t2 = (glo - blo) * 0.0625f;
  float tmin = fminf(t1, t2), tmax = fmaxf(t1, t2);
  int c1 = (int)floorf(tmin), c2 = (int)ceilf(tmax);
  int cand0 = lo, cand1 = hi;
  int cand2 = min(max(c1,     lo), hi);
  int cand3 = min(max(c1 + 1, lo), hi);
  int cand4 = min(max(c2 - 1, lo), hi);
  int cand5 = min(max(c2,     lo), hi);
  float best = -3.0e38f;
  int cands[6] = {cand0, cand1, cand2, cand3, cand4, cand5};
  #pragma unroll
  for (int i = 0; i < 6; i++) {
    float s = (float)(cands[i] << 4);
    float v = fminf(bhi + s, ghi) - fmaxf(blo + s, glo) + 1.0f;
    best = fmaxf(best, v);
  }
  return best;
}

#define AG_LOAD(p)      __hip_atomic_load((p), __ATOMIC_RELAXED, __HIP_MEMORY_SCOPE_AGENT)
#define AG_STORE(p, v)  __hip_atomic_store((p), (v), __ATOMIC_RELAXED, __HIP_MEMORY_SCOPE_AGENT)

__global__ __launch_bounds__(256) void k_one(const float* __restrict__ gt,
                                             const int* __restrict__ imw_p,
                                             const int* __restrict__ imh_p,
                                             float* __restrict__ out_lab,
                                             float* __restrict__ out_adj,
                                             float* __restrict__ out_wts,
                                             uint32_t* __restrict__ ws,
                                             uint32_t kf0, uint32_t kf1,
                                             uint32_t kb0, uint32_t kb1) {
  #pragma clang fp contract(off)
  __shared__ uint64_t scB[GATHER_CAP];       // 16 KB gather/rank buffer
  __shared__ float sg0[NG], sg1[NG], sg2[NG], sg3[NG], sga[NG], sgm[NG];
  __shared__ uint32_t sgmU[NG];
  __shared__ unsigned long long sMask[4];
  __shared__ int sAnyZero, sLastB, sLastD, sOv;
  __shared__ uint32_t sSel[12];
  __shared__ uint32_t sCnt[NGRP], sBase[NGRP], sTot, sBkLo, sBkHi;
  __shared__ uint32_t sCF, sCB;
  int tid = threadIdx.x;
  int b = blockIdx.x;
  int a = b >> 6, hb = (b & 63) << 2;        // anchor type, rows hb..hb+3

  if (tid == 0) { sAnyZero = 0; sCF = 0u; sCB = 0u; }
  if (tid < NG) {
    const float4 g4 = ((const float4*)gt)[tid];
    sg0[tid] = g4.x; sg1[tid] = g4.y; sg2[tid] = g4.z; sg3[tid] = g4.w;
    float gw = g4.z - g4.x + 1.0f, gh = g4.w - g4.y + 1.0f;
    sga[tid] = (gw > 0.0f && gh > 0.0f) ? gw * gh : 0.0f;
    sgmU[tid] = 0u;
  }
  __syncthreads();   // S1

  // ---- local analytic gmax (LDS atomicMax on float bits; IoU >= 0) ----
  {
    int imwi = imw_p[0], imhi = imh_p[0];
    for (int p = tid; p < NG * NUM_A; p += 256) {
      int g = p / NUM_A, q = p - g * NUM_A;
      float b0 = BA[q][0], b1 = BA[q][1], b2 = BA[q][2], b3 = BA[q][3];
      int ib0 = (int)b0, ib1 = (int)b1, ib2 = (int)b2, ib3 = (int)b3;
      int wlo = max(0, (-ib0 + 15) >> 4);
      int whi = min(255, (imwi - ib2 - 1) >> 4);
      int hlo = max(0, (-ib1 + 15) >> 4);
      int hhi = min(255, (imhi - ib3 - 1) >> 4);
      if (wlo > whi || hlo > hhi) continue;
      float iwb = axis_best(b0, b2, sg0[g], sg2[g], wlo, whi);
      float ihb = axis_best(b1, b3, sg1[g], sg3[g], hlo, hhi);
      float aw = b2 - b0 + 1.0f, ah = b3 - b1 + 1.0f;
      float aarea = aw * ah;
      float inter = (iwb > 0.0f && ihb > 0.0f) ? iwb * ihb : 0.0f;
      float den = aarea + sga[g] - inter;
      float o = inter / den;
      atomicMax(&sgmU[g], __float_as_uint(o));
    }
  }

  // per-wave y-mask
  {
    int wv = tid >> 6, g = tid & 63;
    float sy = (float)((hb + wv) << 4);
    float ihp = fminf(BA[a][3] + sy, sg3[g]) - fmaxf(BA[a][1] + sy, sg1[g]) + 1.0f;
    unsigned long long mk = __ballot(ihp > 0.0f);
    if (g == 0) sMask[wv] = mk;
  }
  __syncthreads();   // S2
  if (tid < NG) {
    uint32_t mm = sgmU[tid];
    sgm[tid] = __uint_as_float(mm);
    if (mm == 0u) atomicOr(&sAnyZero, 1);
  }
  __syncthreads();   // S3

  float BA0 = BA[a][0], BA1 = BA[a][1], BA2 = BA[a][2], BA3 = BA[a][3];
  float imw = (float)imw_p[0], imh = (float)imh_p[0];
  int w = tid;
  float sx = (float)(w << 4);
  float A0 = BA0 + sx, A2 = BA2 + sx;
  float aw = A2 - A0 + 1.0f;
  float A1v[4], A3v[4];
  #pragma unroll
  for (int r = 0; r < 4; r++) {
    float sy = (float)((hb + r) << 4);
    A1v[r] = BA1 + sy; A3v[r] = BA3 + sy;
  }
  float ah = A3v[0] - A1v[0] + 1.0f;
  float aarea = aw * ah;
  bool xv = (A0 >= 0.0f) && (A2 < imw);

  unsigned long long mk0 = sMask[0], mk1 = sMask[1],
                     mk2 = sMask[2], mk3 = sMask[3];
  unsigned long long uni = mk0 | mk1 | mk2 | mk3;
  float amaxv[4] = {0.f, 0.f, 0.f, 0.f};
  int bgv[4] = {0, 0, 0, 0};
  uint32_t afv = 0u;
  while (uni) {
    int g = __ffsll(uni) - 1;
    uni &= uni - 1;
    float iw = fminf(A2, sg2[g]) - fmaxf(A0, sg0[g]) + 1.0f;
    if (!__any(iw > 0.0f)) continue;
    if (iw > 0.0f) {
      float base = aarea + sga[g];
      float gy1 = sg1[g], gy2 = sg3[g], gm = sgm[g];
#define DO_ROW(r, mk)                                                     \
      if ((mk >> g) & 1ull) {                                             \
        float ih = fminf(A3v[r], gy2) - fmaxf(A1v[r], gy1) + 1.0f;        \
        float inter = iw * ih;                                            \
        float o = inter / (base - inter);                                 \
        if (o > amaxv[r]) { amaxv[r] = o; bgv[r] = g; }                   \
        if (o == gm) afv |= (1u << r);                                    \
      }
      DO_ROW(0, mk0) DO_ROW(1, mk1) DO_ROW(2, mk2) DO_ROW(3, mk3)
#undef DO_ROW
    }
  }

  bool anyZ = (sAnyZero != 0);
  uint32_t lm[4];
  uint32_t cfLoc = 0, cbLoc = 0;
  #pragma unroll
  for (int r = 0; r < 4; r++) {
    int hw = (hb + r) * 256 + w;
    bool valid = xv && (A1v[r] >= 0.0f) && (A3v[r] < imh);
    float amax = amaxv[r];
    bool anyfg = (((afv >> r) & 1u) || anyZ) && valid;
    uint32_t lab;
    if (!valid)                       lab = LAB_IGN;
    else if (anyfg || amax >= 0.7f)   lab = LAB_FG;
    else if (amax < 0.3f)             lab = LAB_BG;
    else                              lab = LAB_IGN;

    float adj0 = 0.f, adj1 = 0.f, adj2 = 0.f, adj3 = 0.f;
    if (valid) {
      int bg = bgv[r];
      float G0 = sg0[bg], G1 = sg1[bg], G2 = sg2[bg], G3 = sg3[bg];
      float ax = (A2 + A0) * 0.5f, ay = (A3v[r] + A1v[r]) * 0.5f;
      float gwm = G2 - G0 + 1.0f, ghm = G3 - G1 + 1.0f;
      float gx = (G2 + G0) * 0.5f, gy = (G3 + G1) * 0.5f;
      adj0 = (gx - ax) / aw;
      adj1 = (gy - ay) / ah;
      adj2 = logf(gwm / aw);
      adj3 = logf(ghm / ah);
    }
    int c4 = a * 4;
    out_adj[(c4 + 0) * HW + hw] = adj0;
    out_adj[(c4 + 1) * HW + hw] = adj1;
    out_adj[(c4 + 2) * HW + hw] = adj2;
    out_adj[(c4 + 3) * HW + hw] = adj3;

    uint32_t m = 0u;
    uint32_t n = (uint32_t)(hw * 9 + a);
    if (lab != LAB_IGN) {
      uint32_t kk0 = (lab == LAB_FG) ? kf0 : kb0;
      uint32_t kk1 = (lab == LAB_FG) ? kf1 : kb1;
      m = mant_of(kk0, kk1, n);
      if (lab == LAB_FG) cfLoc++; else cbLoc++;
    }
    lm[r] = (lab << 24) | m;                 // stays in registers
  }
  if (cfLoc) atomicAdd(&sCF, cfLoc);
  if (cbLoc) atomicAdd(&sCB, cbLoc);
  __syncthreads();

  // ---- barrier B: publish per-block counts, tree arrival ----
  if (tid == 0) {
    if (sCF) atomicAdd(&ws[OFF_CNTF + (b & 31) * 16], sCF);
    if (sCB) atomicAdd(&ws[OFF_CNTB + (b & 31) * 16], sCB);
    asm volatile("s_waitcnt vmcnt(0)" ::: "memory");
    int last = 0;
    uint32_t v = atomicAdd(&ws[OFF_SUBB + (b & 31) * 16], 1u);
    if (v == 17u) {
      uint32_t q = atomicAdd(&ws[OFF_ROOTB], 1u);
      if (q == 31u) last = 1;
    }
    sLastB = last;
  }
  __syncthreads();
  if (sLastB) {
    // completer B: totals -> K, threshold T per class; publish SELB
    if (tid < 32)       sCnt[tid] = AG_LOAD(&ws[OFF_CNTF + tid * 16]);
    else if (tid < 64)  sBase[tid - 32] = AG_LOAD(&ws[OFF_CNTB + (tid - 32) * 16]);
    __syncthreads();
    if (tid == 0) {
      uint32_t tf = 0, tb = 0;
      for (int i = 0; i < 32; i++) { tf += sCnt[i]; tb += sBase[i]; }
      uint32_t Kf_ = tf < CAPK ? tf : CAPK;
      uint32_t Kb_ = tb < CAPK ? tb : CAPK;
      uint32_t Tf_ = (tf <= TARGETC) ? TFULL
                   : (uint32_t)(((unsigned long long)TARGETC << 23) / tf);
      uint32_t Tb_ = (tb <= TARGETC) ? TFULL
                   : (uint32_t)(((unsigned long long)TARGETC << 23) / tb);
      if (Tf_ == 0u) Tf_ = 1u;
      if (Tb_ == 0u) Tb_ = 1u;
      AG_STORE(&ws[OFF_SELB + 0], Tf_); AG_STORE(&ws[OFF_SELB + 1], Tb_);
      AG_STORE(&ws[OFF_SELB + 2], Kf_); AG_STORE(&ws[OFF_SELB + 3], Kb_);
      AG_STORE(&ws[OFF_SELB + 4], tf);  AG_STORE(&ws[OFF_SELB + 5], tb);
    }
    asm volatile("s_waitcnt vmcnt(0)" ::: "memory");
    __syncthreads();
    // broadcast: per-BLOCK flags, 256 threads in parallel (1 poller/addr)
    for (int i = tid; i < NBLK; i += 256) AG_STORE(&ws[OFF_WAKEB + i * 16], 1u);
  }

  // ---- wake B: poll OWN per-block flag (zero contention) ----
  if (tid == 0) {
    while (AG_LOAD(&ws[OFF_WAKEB + b * 16]) == 0u)
      __builtin_amdgcn_s_sleep(8);
  }
  __syncthreads();
  if (tid < 6) sSel[tid] = AG_LOAD(&ws[OFF_SELB + tid]);
  __syncthreads();
  uint32_t Tc[2] = {sSel[0], sSel[1]};       // cls 0 = FG, 1 = BG
  uint32_t Kf = sSel[2], Kb = sSel[3], totF = sSel[4], totB = sSel[5];
  float inv = 1.0f / (float)(Kf + Kb);       // 1/num_ni (unused if 0 kept)

  // ---- round loop: push keys < T, completer ranks exact K-th key ----
  uint32_t modeF = 0u, modeB = 0u;           // 0 NONE, 1 ALL, 2 THRESH
  uint64_t bkF = 0ull, bkB = 0ull;
  bool doneSel = false;
  for (int rnd = 0; rnd < R_MAX && !doneSel; rnd++) {
    uint32_t base = OFF_RND + (uint32_t)rnd * RSTRIDE;
    // push
    #pragma unroll
    for (int r = 0; r < 4; r++) {
      uint32_t lab = lm[r] >> 24;
      if (lab == LAB_IGN) continue;
      uint32_t m = lm[r] & 0x7FFFFFu;
      int cls = (lab == LAB_FG) ? 0 : 1;
      if (m < Tc[cls]) {
        int hw = (hb + r) * 256 + w;
        uint32_t n = (uint32_t)(hw * 9 + a);
        uint32_t grp = (n * 2654435761u) >> 27;      // uniform hash group
        uint32_t idx = atomicAdd(
            &ws[base + (cls ? R_PCNTB : R_PCNTF) + grp * 16], 1u);
        if (idx < GCAP) {
          uint64_t* lst =
              (uint64_t*)(ws + (cls ? OFF_LISTB : OFF_LISTF)) + grp * GCAP;
          AG_STORE(&lst[idx], ((uint64_t)m << 20) | (uint64_t)n);
        }
      }
    }
    asm volatile("s_waitcnt vmcnt(0)" ::: "memory");
    __syncthreads();
    // arrival D_rnd
    if (tid == 0) {
      int last = 0;
      uint32_t v = atomicAdd(&ws[base + R_SUBD + (b & 31) * 16], 1u);
      if (v == 17u) {
        uint32_t q = atomicAdd(&ws[base + R_ROOTD], 1u);
        if (q == 31u) last = 1;
      }
      sLastD = last;
    }
    __syncthreads();
    if (sLastD) {
      uint32_t modes[2]; uint64_t bks[2]; int oks[2];
      uint32_t Cs[2]; int ovs[2];
      for (int cls = 0; cls < 2; cls++) {
        uint32_t Kc = cls ? Kb : Kf;
        uint32_t totc = cls ? totB : totF;
        if (tid < 32)
          sCnt[tid] = AG_LOAD(&ws[base + (cls ? R_PCNTB : R_PCNTF) + tid * 16]);
        __syncthreads();
        if (tid == 0) {
          uint32_t acc = 0; int ov = 0;
          for (int g2 = 0; g2 < NGRP; g2++) {
            uint32_t c2 = sCnt[g2];
            if (c2 > GCAP) { ov = 1; c2 = GCAP; }
            sBase[g2] = acc; acc += c2;
          }
          sTot = acc; sOv = ov;
        }
        __syncthreads();
        uint32_t C = sTot; int ov = sOv;
        uint32_t mode = 0u; uint64_t bk = 0ull; int ok = 1;
        if (Kc == 0u) { ok = 1; mode = 0u; }
        else if (totc <= CAPK) { ok = (!ov && C == totc); mode = 1u; }
        else {
          ok = (!ov && C >= Kc && C <= CLIMIT &&
                (totc > TARGETC || C == totc));
          mode = 2u;
        }
        if (ok && mode == 2u) {
          const uint64_t* lst0 =
              (const uint64_t*)(ws + (cls ? OFF_LISTB : OFF_LISTF));
          for (uint32_t idx = tid; idx < NGRP * GCAP; idx += 256) {
            uint32_t g2 = idx >> 8, i = idx & 255u;     // GCAP = 256
            if (i < sCnt[g2]) {
              uint32_t dst = sBase[g2] + i;
              if (dst < GATHER_CAP)
                scB[dst] = AG_LOAD(&lst0[g2 * GCAP + i]);
            }
          }
          __syncthreads();
          for (uint32_t i = tid; i < C; i += 256) {
            uint64_t k = scB[i];
            uint32_t rr = 0;
            for (uint32_t j = 0; j < C; j++) rr += (scB[j] < k) ? 1u : 0u;
            if (rr == Kc - 1u) {                 // exact K-th smallest
              sBkLo = (uint32_t)k; sBkHi = (uint32_t)(k >> 32);
            }
          }
          __syncthreads();
          bk = ((uint64_t)sBkHi << 32) | (uint64_t)sBkLo;
        }
        modes[cls] = mode; bks[cls] = bk; oks[cls] = ok;
        Cs[cls] = C; ovs[cls] = ov;
        __syncthreads();
      }
      uint32_t st = (oks[0] && oks[1]) ? 1u : 2u;
      uint32_t TN[2];
      for (int cls = 0; cls < 2; cls++) {
        uint32_t t = Tc[cls];
        if (!oks[cls]) {
          if (ovs[cls] || Cs[cls] > CLIMIT) t = (t > 1u) ? (t >> 1) : 1u;
          else { t = (t >= (TFULL >> 2)) ? TFULL : (t << 2); }
        }
        TN[cls] = t;
      }
      if (tid == 0) {
        AG_STORE(&ws[base + R_DCMD + 0], st);
        AG_STORE(&ws[base + R_DCMD + 1], modes[0]);
        AG_STORE(&ws[base + R_DCMD + 2], (uint32_t)bks[0]);
        AG_STORE(&ws[base + R_DCMD + 3], (uint32_t)(bks[0] >> 32));
        AG_STORE(&ws[base + R_DCMD + 4], modes[1]);
        AG_STORE(&ws[base + R_DCMD + 5], (uint32_t)bks[1]);
        AG_STORE(&ws[base + R_DCMD + 6], (uint32_t)(bks[1] >> 32));
        AG_STORE(&ws[base + R_DCMD + 7], TN[0]);
        AG_STORE(&ws[base + R_DCMD + 8], TN[1]);
      }
      asm volatile("s_waitcnt vmcnt(0)" ::: "memory");
      __syncthreads();
      // broadcast per-BLOCK round flags (value rnd+1; rounds can't alias)
      for (int i = tid; i < NBLK; i += 256)
        AG_STORE(&ws[OFF_WAKED + i * 16], (uint32_t)(rnd + 1));
    }
    // wake D_rnd: poll OWN per-block flag (zero contention)
    if (tid == 0) {
      while (AG_LOAD(&ws[OFF_WAKED + b * 16]) != (uint32_t)(rnd + 1))
        __builtin_amdgcn_s_sleep(8);
    }
    __syncthreads();
    if (tid < 9) sSel[tid] = AG_LOAD(&ws[base + R_DCMD + tid]);
    __syncthreads();
    if (sSel[0] == 1u) {
      modeF = sSel[1]; bkF = ((uint64_t)sSel[3] << 32) | (uint64_t)sSel[2];
      modeB = sSel[4]; bkB = ((uint64_t)sSel[6] << 32) | (uint64_t)sSel[5];
      doneSel = true;
    } else {
      Tc[0] = sSel[7]; Tc[1] = sSel[8];
    }
    __syncthreads();
  }

  // ---- emit: kept <=> key <= K-th smallest key (exact, sole writers) ----
  #pragma unroll
  for (int r = 0; r < 4; r++) {
    int hw = (hb + r) * 256 + w;
    uint32_t lab = lm[r] >> 24;
    uint32_t m = lm[r] & 0x7FFFFFu;
    uint32_t n = (uint32_t)(hw * 9 + a);
    uint64_t key = ((uint64_t)m << 20) | (uint64_t)n;
    float outv = 2.0f, wv = 0.0f;
    if (lab == LAB_FG) {
      bool kept = (modeF == 1u) || (modeF == 2u && key <= bkF);
      if (kept) { outv = 1.0f; wv = inv; }
    } else if (lab == LAB_BG) {
      bool kept = (modeB == 1u) || (modeB == 2u && key <= bkB);
      if (kept) outv = 0.0f;
    }
    out_lab[a * HW + hw] = outv;
    int c4 = a * 4;
    out_wts[(c4 + 0) * HW + hw] = wv;
    out_wts[(c4 + 1) * HW + hw] = wv;
    out_wts[(c4 + 2) * HW + hw] = wv;
    out_wts[(c4 + 3) * HW + hw] = wv;
  }
}

extern "C" void kernel_launch(void* const* d_in, const int* in_sizes, int n_in,
                              void* d_out, int out_size, void* d_ws,
                              size_t ws_size, hipStream_t stream) {
  const float* gt  = (const float*)d_in[1];
  const int*   imw = (const int*)d_in[2];
  const int*   imh = (const int*)d_in[3];
  float* out      = (float*)d_out;
  float* out_lab  = out;                   // 589824
  float* out_adj  = out + N_ANCH;          // 4*589824
  float* out_wts  = out + 5 * N_ANCH;      // 4*589824
  uint32_t* ws = (uint32_t*)d_ws;          // ~261 KB used

  uint32_t kf0, kf1, kb0, kb1;
  tf2x32(0u, 42u, 0u, 0u, &kf0, &kf1);
  tf2x32(0u, 42u, 0u, 1u, &kb0, &kb1);

  // Stream-ordered zero of ctrl region (counts, barriers, per-block wake
  // flags, per-round push counters): every run starts clean.
  hipMemsetAsync(ws, 0, CTRL_WORDS * sizeof(uint32_t), stream);
  // Residency by capacity: 576 blocks, ~18KB LDS -> 8 blocks/CU (2048
  // slots) >> 576; sole kernel on the stream -> all co-resident.
  hipLaunchKernelGGL(k_one, dim3(NBLK), dim3(256), 0, stream, gt, imw, imh,
                     out_lab, out_adj, out_wts, ws, kf0, kf1, kb0, kb1);
}

// Round 13
// 93.033 us; speedup vs baseline: 2.4453x; 2.4195x over previous
//
#include <hip/hip_runtime.h>
#include <stdint.h>

// ===========================================================================
// AnchorDataGenerator (Faster R-CNN anchor target layer), MI355X / gfx950
// Round 16 = Round-8 champion (98.8us, absmax 0) with ONE change:
// the full-range 2048-bin global hist (~400K IF atomics, ~20-25us,
// throughput-bound) is replaced by a coarse-filtered 256-bin hist:
//   FG: all keys, bin = m >> 15 (totF small)
//   BG: only keys with m < 2^16, bin = m >> 8  (~3.5K entries chip-wide;
//       128th-smallest << 2^16 with ~25x margin for this op's geometry;
//       m >= 2^16 provably outside top-128 whenever boundary bin < 256)
// K now comes from per-block class totals (2 fanned atomics/block, code
// proven in R14). totX <= 128 -> exact keep-ALL mode.
// EVERYTHING ELSE BYTE-EQUIVALENT to the champion: one tree barrier B,
// completer select, 32-flag CFLAG wake, emit with boundary-bin candidate
// push (single counters), tree barrier D, completer fixup (exact rank on
// full keys), vmcnt(0) before every arrival RMW, memset+worker dispatch.
// This is also the decisive experiment for the R14/R15 mystery: differs
// from champion ONLY in hist mass; from R14 ONLY in sync structure.
// ===========================================================================

#define NUM_A 9
#define HW 65536
#define N_ANCH 589824
#define NG 64
#define CAPK 128u
#define NBINS 256
#define BG_TC 65536u                     // BG coarse filter threshold on m
#define CAND_CAP 2048

#define LAB_BG 0u
#define LAB_FG 1u
#define LAB_IGN 2u

#define NBLK 576

// workspace layout (u32 words)
#define OFF_HF    0                      // 256 fg hist (full range, >>15)
#define OFF_HB    256                    // 256 bg hist ([0,2^16), >>8)
#define OFF_TOTF  512                    // 32 x stride16 per-group fg totals
#define OFF_TOTB  1024                   // 32 x stride16 bg totals
#define OFF_SUBB  1536                   // 32 x stride16 barrier-B subs
#define OFF_ROOTB 2048                   // (pad 16)
#define OFF_SUBD  2064                   // 32 x stride16 barrier-D subs
#define OFF_ROOTD 2576                   // (pad 16)
#define OFF_SEL   2592                   // 10 used: {mode,bin,below,need,K}x2
#define OFF_CFLG  2608                   // 32 x stride16 wake flags
#define OFF_CNTF  3120                   // candidate counter fg (pad 16)
#define OFF_CNTB  3136                   // candidate counter bg (pad 16)
#define CTRL_WORDS 3152                  // 12.6 KB memset
#define OFF_CANDF CTRL_WORDS             // 3152 (byte 12608, 8B aligned)
#define OFF_CANDB (OFF_CANDF + 2*CAND_CAP)   // 7248; end 11344 (~45 KB)

#define MAGIC_C 0x5CA1AB1Eu

__constant__ float BA[NUM_A][4] = {
  { -84.f,  -40.f,  99.f,  55.f}, {-176.f,  -88.f, 191.f, 103.f},
  {-360.f, -184.f, 375.f, 199.f}, { -56.f,  -56.f,  71.f,  71.f},
  {-120.f, -120.f, 135.f, 135.f}, {-248.f, -248.f, 263.f, 263.f},
  { -36.f,  -80.f,  51.f,  95.f}, { -80.f, -168.f,  95.f, 183.f},
  {-168.f, -344.f, 183.f, 359.f}};

__host__ __device__ static inline void tf2x32(uint32_t k0, uint32_t k1,
                                              uint32_t x0, uint32_t x1,
                                              uint32_t* o0, uint32_t* o1) {
  const uint32_t ks2 = k0 ^ k1 ^ 0x1BD11BDAu;
#define TF_R(r) { x0 += x1; x1 = (x1 << (r)) | (x1 >> (32 - (r))); x1 ^= x0; }
  x0 += k0; x1 += k1;
  TF_R(13) TF_R(15) TF_R(26) TF_R(6)
  x0 += k1;  x1 += ks2 + 1u;
  TF_R(17) TF_R(29) TF_R(16) TF_R(24)
  x0 += ks2; x1 += k0 + 2u;
  TF_R(13) TF_R(15) TF_R(26) TF_R(6)
  x0 += k0;  x1 += k1 + 3u;
  TF_R(17) TF_R(29) TF_R(16) TF_R(24)
  x0 += k1;  x1 += ks2 + 4u;
  TF_R(13) TF_R(15) TF_R(26) TF_R(6)
  x0 += ks2; x1 += k0 + 5u;
#undef TF_R
  *o0 = x0; *o1 = x1;
}

__device__ static inline uint32_t mant_of(uint32_t k0, uint32_t k1, uint32_t n) {
  uint32_t o0, o1;
  tf2x32(k0, k1, 0u, n, &o0, &o1);
  return (o0 ^ o1) >> 9;                 // 23-bit mantissa
}

// Max of fl(iw) over valid integer shifts [lo,hi] for one axis (concave,
// unimodal; max at clamped floor/ceil of continuous argmax endpoints).
__device__ static inline float axis_best(float blo, float bhi, float glo,
                                         float ghi, int lo, int hi) {
  #pragma clang fp contract(off)
  float t1 = (ghi - bhi) * 0.0625f;
  float t2 = (glo - blo) * 0.0625f;
  float tmin = fminf(t1, t2), tmax = fmaxf(t1, t2);
  int c1 = (int)floorf(tmin), c2 = (int)ceilf(tmax);
  int cand0 = lo, cand1 = hi;
  int cand2 = min(max(c1,     lo), hi);
  int cand3 = min(max(c1 + 1, lo), hi);
  int cand4 = min(max(c2 - 1, lo), hi);
  int cand5 = min(max(c2,     lo), hi);
  float best = -3.0e38f;
  int cands[6] = {cand0, cand1, cand2, cand3, cand4, cand5};
  #pragma unroll
  for (int i = 0; i < 6; i++) {
    float s = (float)(cands[i] << 4);
    float v = fminf(bhi + s, ghi) - fmaxf(blo + s, glo) + 1.0f;
    best = fmaxf(best, v);
  }
  return best;
}

#define AG_LOAD(p)      __hip_atomic_load((p), __ATOMIC_RELAXED, __HIP_MEMORY_SCOPE_AGENT)
#define AG_STORE(p, v)  __hip_atomic_store((p), (v), __ATOMIC_RELAXED, __HIP_MEMORY_SCOPE_AGENT)

__global__ __launch_bounds__(256) void k_one(const float* __restrict__ gt,
                                             const int* __restrict__ imw_p,
                                             const int* __restrict__ imh_p,
                                             float* __restrict__ out_lab,
                                             float* __restrict__ out_adj,
                                             float* __restrict__ out_wts,
                                             uint32_t* __restrict__ ws,
                                             uint32_t kf0, uint32_t kf1,
                                             uint32_t kb0, uint32_t kb1) {
  #pragma clang fp contract(off)
  __shared__ uint64_t scB[CAND_CAP];         // 16 KB; hist+scan view aliased
  uint32_t* sh = (uint32_t*)scB;             // [0..511] LDS hist, scan buf
  __shared__ float sg0[NG], sg1[NG], sg2[NG], sg3[NG], sga[NG], sgm[NG];
  __shared__ uint32_t sgmU[NG];
  __shared__ unsigned long long sMask[4];
  __shared__ int sAnyZero, sLastB, sLastD;
  __shared__ uint32_t sSel[10];
  __shared__ uint32_t sCF, sCB;
  int tid = threadIdx.x;
  int b = blockIdx.x;
  int a = b >> 6, hb = (b & 63) << 2;        // anchor type, rows hb..hb+3

  ((uint2*)sh)[tid] = make_uint2(0, 0);      // zero 512-word LDS hist
  if (tid == 0) { sAnyZero = 0; sCF = 0u; sCB = 0u; }
  if (tid < NG) {
    const float4 g4 = ((const float4*)gt)[tid];
    sg0[tid] = g4.x; sg1[tid] = g4.y; sg2[tid] = g4.z; sg3[tid] = g4.w;
    float gw = g4.z - g4.x + 1.0f, gh = g4.w - g4.y + 1.0f;
    sga[tid] = (gw > 0.0f && gh > 0.0f) ? gw * gh : 0.0f;
    sgmU[tid] = 0u;
  }
  __syncthreads();   // S1

  // ---- local analytic gmax (LDS atomicMax on float bits; IoU >= 0) ----
  {
    int imwi = imw_p[0], imhi = imh_p[0];
    for (int p = tid; p < NG * NUM_A; p += 256) {
      int g = p / NUM_A, q = p - g * NUM_A;
      float b0 = BA[q][0], b1 = BA[q][1], b2 = BA[q][2], b3 = BA[q][3];
      int ib0 = (int)b0, ib1 = (int)b1, ib2 = (int)b2, ib3 = (int)b3;
      int wlo = max(0, (-ib0 + 15) >> 4);
      int whi = min(255, (imwi - ib2 - 1) >> 4);
      int hlo = max(0, (-ib1 + 15) >> 4);
      int hhi = min(255, (imhi - ib3 - 1) >> 4);
      if (wlo > whi || hlo > hhi) continue;
      float iwb = axis_best(b0, b2, sg0[g], sg2[g], wlo, whi);
      float ihb = axis_best(b1, b3, sg1[g], sg3[g], hlo, hhi);
      float aw = b2 - b0 + 1.0f, ah = b3 - b1 + 1.0f;
      float aarea = aw * ah;
      float inter = (iwb > 0.0f && ihb > 0.0f) ? iwb * ihb : 0.0f;
      float den = aarea + sga[g] - inter;
      float o = inter / den;
      atomicMax(&sgmU[g], __float_as_uint(o));
    }
  }

  // per-wave y-mask
  {
    int wv = tid >> 6, g = tid & 63;
    float sy = (float)((hb + wv) << 4);
    float ihp = fminf(BA[a][3] + sy, sg3[g]) - fmaxf(BA[a][1] + sy, sg1[g]) + 1.0f;
    unsigned long long mk = __ballot(ihp > 0.0f);
    if (g == 0) sMask[wv] = mk;
  }
  __syncthreads();   // S2
  if (tid < NG) {
    uint32_t mm = sgmU[tid];
    sgm[tid] = __uint_as_float(mm);
    if (mm == 0u) atomicOr(&sAnyZero, 1);
  }
  __syncthreads();   // S3

  float BA0 = BA[a][0], BA1 = BA[a][1], BA2 = BA[a][2], BA3 = BA[a][3];
  float imw = (float)imw_p[0], imh = (float)imh_p[0];
  int w = tid;
  float sx = (float)(w << 4);
  float A0 = BA0 + sx, A2 = BA2 + sx;
  float aw = A2 - A0 + 1.0f;
  float A1v[4], A3v[4];
  #pragma unroll
  for (int r = 0; r < 4; r++) {
    float sy = (float)((hb + r) << 4);
    A1v[r] = BA1 + sy; A3v[r] = BA3 + sy;
  }
  float ah = A3v[0] - A1v[0] + 1.0f;
  float aarea = aw * ah;                   // exact ints -> bit-exact
  bool xv = (A0 >= 0.0f) && (A2 < imw);

  unsigned long long mk0 = sMask[0], mk1 = sMask[1],
                     mk2 = sMask[2], mk3 = sMask[3];
  unsigned long long uni = mk0 | mk1 | mk2 | mk3;
  float amaxv[4] = {0.f, 0.f, 0.f, 0.f};
  int bgv[4] = {0, 0, 0, 0};
  uint32_t afv = 0u;
  while (uni) {
    int g = __ffsll(uni) - 1;
    uni &= uni - 1;
    float iw = fminf(A2, sg2[g]) - fmaxf(A0, sg0[g]) + 1.0f;
    if (!__any(iw > 0.0f)) continue;
    if (iw > 0.0f) {
      float base = aarea + sga[g];
      float gy1 = sg1[g], gy2 = sg3[g], gm = sgm[g];
#define DO_ROW(r, mk)                                                     \
      if ((mk >> g) & 1ull) {                                             \
        float ih = fminf(A3v[r], gy2) - fmaxf(A1v[r], gy1) + 1.0f;        \
        float inter = iw * ih;                                            \
        float o = inter / (base - inter);                                 \
        if (o > amaxv[r]) { amaxv[r] = o; bgv[r] = g; }                   \
        if (o == gm) afv |= (1u << r);                                    \
      }
      DO_ROW(0, mk0) DO_ROW(1, mk1) DO_ROW(2, mk2) DO_ROW(3, mk3)
#undef DO_ROW
    }
  }

  bool anyZ = (sAnyZero != 0);
  uint32_t lm[4];
  uint32_t cfLoc = 0, cbLoc = 0;
  #pragma unroll
  for (int r = 0; r < 4; r++) {
    int hw = (hb + r) * 256 + w;
    bool valid = xv && (A1v[r] >= 0.0f) && (A3v[r] < imh);
    float amax = amaxv[r];
    bool anyfg = (((afv >> r) & 1u) || anyZ) && valid;
    uint32_t lab;
    if (!valid)                       lab = LAB_IGN;
    else if (anyfg || amax >= 0.7f)   lab = LAB_FG;
    else if (amax < 0.3f)             lab = LAB_BG;
    else                              lab = LAB_IGN;

    float adj0 = 0.f, adj1 = 0.f, adj2 = 0.f, adj3 = 0.f;
    if (valid) {
      int bg = bgv[r];
      float G0 = sg0[bg], G1 = sg1[bg], G2 = sg2[bg], G3 = sg3[bg];
      float ax = (A2 + A0) * 0.5f, ay = (A3v[r] + A1v[r]) * 0.5f;
      float gwm = G2 - G0 + 1.0f, ghm = G3 - G1 + 1.0f;
      float gx = (G2 + G0) * 0.5f, gy = (G3 + G1) * 0.5f;
      adj0 = (gx - ax) / aw;
      adj1 = (gy - ay) / ah;
      adj2 = logf(gwm / aw);
      adj3 = logf(ghm / ah);
    }
    int c4 = a * 4;
    out_adj[(c4 + 0) * HW + hw] = adj0;
    out_adj[(c4 + 1) * HW + hw] = adj1;
    out_adj[(c4 + 2) * HW + hw] = adj2;
    out_adj[(c4 + 3) * HW + hw] = adj3;

    uint32_t m = 0u;
    uint32_t n = (uint32_t)(hw * 9 + a);   // original anchor index (tie-break)
    if (lab != LAB_IGN) {
      uint32_t kk0 = (lab == LAB_FG) ? kf0 : kb0;
      uint32_t kk1 = (lab == LAB_FG) ? kf1 : kb1;
      m = mant_of(kk0, kk1, n);
      if (lab == LAB_FG) {
        cfLoc++;
        atomicAdd(&sh[m >> 15], 1u);                   // FG: full range >>15
      } else {
        cbLoc++;
        if (m < BG_TC) atomicAdd(&sh[NBINS + (m >> 8)], 1u);  // BG: coarse
      }
    }
    lm[r] = (lab << 24) | m;                 // stays in registers
  }
  if (cfLoc) atomicAdd(&sCF, cfLoc);
  if (cbLoc) atomicAdd(&sCB, cbLoc);
  __syncthreads();

  // ---- global hist add (~9 atomics/block) + per-block totals ----
  for (int i = tid; i < 2 * NBINS; i += 256) {
    uint32_t v = sh[i];
    if (v) atomicAdd(&ws[OFF_HF + i], v);
  }
  if (tid == 0) {
    if (sCF) atomicAdd(&ws[OFF_TOTF + (b & 31) * 16], sCF);
    if (sCB) atomicAdd(&ws[OFF_TOTB + (b & 31) * 16], sCB);
  }
  asm volatile("s_waitcnt vmcnt(0)" ::: "memory");
  __syncthreads();

  // ---- barrier B: tree arrival; completer runs select ----
  if (tid == 0) {
    int last = 0;
    uint32_t v = atomicAdd(&ws[OFF_SUBB + (b & 31) * 16], 1u);
    if (v == 17u) {
      uint32_t r = atomicAdd(&ws[OFF_ROOTB], 1u);
      if (r == 31u) last = 1;
    }
    sLastB = last;
  }
  __syncthreads();
  if (sLastB) {
    // totals: 64 counters loaded in parallel, reduced via LDS
    __shared__ uint32_t sTots[64];
    if (tid < 32)       sTots[tid] = AG_LOAD(&ws[OFF_TOTF + tid * 16]);
    else if (tid < 64)  sTots[tid] = AG_LOAD(&ws[OFF_TOTB + (tid - 32) * 16]);
    __syncthreads();
    uint32_t totF = 0, totB = 0;
    if (tid == 0) {
      for (int i = 0; i < 32; i++) { totF += sTots[i]; totB += sTots[32 + i]; }
      sTots[0] = totF; sTots[1] = totB;
    }
    __syncthreads();
    totF = sTots[0]; totB = sTots[1];

    for (int cls = 0; cls < 2; cls++) {
      uint32_t* hist = ws + (cls ? OFF_HB : OFF_HF);
      uint32_t* sel = ws + OFF_SEL + cls * 5;
      uint32_t tot = cls ? totB : totF;
      uint32_t K = tot < CAPK ? tot : CAPK;
      uint32_t loc = AG_LOAD(&hist[tid]);      // 1 bin/thread, parallel
      sh[tid] = loc; __syncthreads();
      for (int off = 1; off < 256; off <<= 1) {
        uint32_t v = (tid >= off) ? sh[tid - off] : 0u;
        __syncthreads();
        sh[tid] += v;
        __syncthreads();
      }
      if (tid == 0) {
        uint32_t mode = (K == 0u) ? 0u : ((tot <= CAPK) ? 1u : 2u);
        AG_STORE(&sel[0], mode);
        AG_STORE(&sel[4], K);
        if (mode != 2u) {
          AG_STORE(&sel[1], 0xFFFFFFFFu); AG_STORE(&sel[2], 0u);
          AG_STORE(&sel[3], 0u);
        }
      }
      if (K > 0u && tot > CAPK) {
        uint32_t myC = sh[tid], pvC = (tid == 0) ? 0u : sh[tid - 1];
        if (myC >= K && pvC < K) {            // boundary bin = tid
          AG_STORE(&sel[1], (uint32_t)tid); AG_STORE(&sel[2], pvC);
          AG_STORE(&sel[3], K - pvC);
        }
      }
      __syncthreads();
    }
    asm volatile("s_waitcnt vmcnt(0)" ::: "memory");
    __syncthreads();                         // all SEL stores at IF
    if (tid < 32) AG_STORE(&ws[OFF_CFLG + tid * 16], MAGIC_C);
  }

  // ---- fanned-out wake: poll OWN sub-flag (<=18 pollers/address) ----
  if (tid == 0) {
    while (AG_LOAD(&ws[OFF_CFLG + (b & 31) * 16]) != MAGIC_C)
      __builtin_amdgcn_s_sleep(2);
  }
  __syncthreads();
  if (tid < 10) sSel[tid] = AG_LOAD(&ws[OFF_SEL + tid]);
  __syncthreads();
  uint32_t mF = sSel[0], bbF = sSel[1];
  uint32_t mB = sSel[5], bbB = sSel[6];
  uint32_t Kf = sSel[4], Kb = sSel[9];
  float inv = 1.0f / (float)(Kf + Kb);       // 1/num_ni

  // ---- emit; boundary-bin anchors deferred to completer fixup ----
  #pragma unroll
  for (int r = 0; r < 4; r++) {
    int hw = (hb + r) * 256 + w;
    uint32_t lab = lm[r] >> 24;
    uint32_t m = lm[r] & 0x7FFFFFu;
    uint32_t n = (uint32_t)(hw * 9 + a);
    float outv = 2.0f, wv = 0.0f;
    bool skip = false;                        // true -> fixup sole writer
    if (lab == LAB_FG) {
      if (mF == 1u) { outv = 1.0f; wv = inv; }
      else if (mF == 2u) {
        uint32_t bn = m >> 15;
        if (bn < bbF) { outv = 1.0f; wv = inv; }
        else if (bn == bbF) {
          uint32_t idx = atomicAdd(&ws[OFF_CNTF], 1u);
          if (idx < CAND_CAP) {
            AG_STORE((uint64_t*)(ws + OFF_CANDF) + idx,
                     ((uint64_t)m << 20) | (uint64_t)n);
            skip = true;
          }
        }
      }
    } else if (lab == LAB_BG) {
      if (mB == 1u) { outv = 0.0f; }
      else if (mB == 2u && m < BG_TC) {
        uint32_t bn = m >> 8;
        if (bn < bbB) { outv = 0.0f; }
        else if (bn == bbB) {
          uint32_t idx = atomicAdd(&ws[OFF_CNTB], 1u);
          if (idx < CAND_CAP) {
            AG_STORE((uint64_t*)(ws + OFF_CANDB) + idx,
                     ((uint64_t)m << 20) | (uint64_t)n);
            skip = true;
          }
        }
      }
    }
    if (!skip) {
      out_lab[a * HW + hw] = outv;
      int c4 = a * 4;
      out_wts[(c4 + 0) * HW + hw] = wv;
      out_wts[(c4 + 1) * HW + hw] = wv;
      out_wts[(c4 + 2) * HW + hw] = wv;
      out_wts[(c4 + 3) * HW + hw] = wv;
    }
  }

  asm volatile("s_waitcnt vmcnt(0)" ::: "memory");
  __syncthreads();

  // ---- barrier D: tree arrival; completer runs fixup; others exit ----
  if (tid == 0) {
    int last = 0;
    uint32_t v = atomicAdd(&ws[OFF_SUBD + (b & 31) * 16], 1u);
    if (v == 17u) {
      uint32_t r = atomicAdd(&ws[OFF_ROOTD], 1u);
      if (r == 31u) last = 1;
    }
    sLastD = last;
  }
  __syncthreads();
  if (sLastD) {
    for (int cls = 0; cls < 2; cls++) {
      uint32_t cnt = AG_LOAD(&ws[cls == 0 ? OFF_CNTF : OFF_CNTB]);
      uint32_t C = cnt < CAND_CAP ? cnt : CAND_CAP;
      uint32_t need = AG_LOAD(&ws[OFF_SEL + cls * 5 + 3]);
      const uint64_t* cand =
          (const uint64_t*)(ws + (cls == 0 ? OFF_CANDF : OFF_CANDB));
      for (uint32_t i = tid; i < C; i += 256)
        scB[i] = AG_LOAD(&cand[i]);           // parallel gather (R13 lesson)
      __syncthreads();
      for (uint32_t i = tid; i < C; i += 256) {
        uint64_t k = scB[i];
        uint32_t rr = 0;
        for (uint32_t j = 0; j < C; j++) rr += (scB[j] < k) ? 1u : 0u;
        bool kept = (rr < need);             // keys unique -> exactly need
        uint32_t nn = (uint32_t)(k & 0xFFFFFu);
        uint32_t aa = nn % 9u, hww = nn / 9u;
        uint32_t tt = aa * HW + hww;
        float lv = kept ? (cls == 0 ? 1.0f : 0.0f) : 2.0f;
        float wvv = (kept && cls == 0) ? inv : 0.0f;
        AG_STORE(&out_lab[tt], lv);
        #pragma unroll
        for (int j2 = 0; j2 < 4; j2++)
          AG_STORE(&out_wts[(aa * 4 + j2) * HW + hww], wvv);
      }
      __syncthreads();
    }
  }
}

extern "C" void kernel_launch(void* const* d_in, const int* in_sizes, int n_in,
                              void* d_out, int out_size, void* d_ws,
                              size_t ws_size, hipStream_t stream) {
  const float* gt  = (const float*)d_in[1];
  const int*   imw = (const int*)d_in[2];
  const int*   imh = (const int*)d_in[3];
  float* out      = (float*)d_out;
  float* out_lab  = out;                   // 589824
  float* out_adj  = out + N_ANCH;          // 4*589824
  float* out_wts  = out + 5 * N_ANCH;      // 4*589824
  uint32_t* ws = (uint32_t*)d_ws;          // ~45 KB used

  uint32_t kf0, kf1, kb0, kb1;
  tf2x32(0u, 42u, 0u, 0u, &kf0, &kf1);
  tf2x32(0u, 42u, 0u, 1u, &kb0, &kb1);

  // Stream-ordered zero of ctrl region (hists, totals, barriers, SEL,
  // CFLG, candidate counters): every run starts clean.
  hipMemsetAsync(ws, 0, CTRL_WORDS * sizeof(uint32_t), stream);
  // Residency by capacity: 576 blocks, ~18KB LDS -> 8 blocks/CU (2048
  // slots) >> 576; sole kernel on the stream -> all co-resident.
  hipLaunchKernelGGL(k_one, dim3(NBLK), dim3(256), 0, stream, gt, imw, imh,
                     out_lab, out_adj, out_wts, ws, kf0, kf1, kb0, kb1);
}

// Round 14
// 91.121 us; speedup vs baseline: 2.4966x; 1.0210x over previous
//
#include <hip/hip_runtime.h>
#include <stdint.h>

// ===========================================================================
// AnchorDataGenerator (Faster R-CNN anchor target layer), MI355X / gfx950
// Round 17 = Round-16 champion (93.0us, absmax 0) with ONE change:
// the memset dispatch is folded into k_one (saves 1 dispatch + boundary,
// ~10us). Poison-safe self-init (fixes R10's lifecycle bug):
//   - block 0 zeroes the ctrl region via AGENT-SCOPE ATOMIC stores (at IF,
//     immune to dirty-L2 writeback clobber), vmcnt(0), then publishes 32
//     fanned ZFLAG words = MAGIC_Z. ZFLAG lives OUTSIDE the zeroed region.
//   - every block polls its group ZFLAG before its FIRST ctrl access (the
//     hist add, ~10us into compute) -> gate is pre-satisfied in practice.
//   - the fixup completer ZEROES ZFLAG at kernel end. Lifecycle: poison ->
//     garbage != MAGIC -> wait (correct); run->run without poison -> prev
//     completer zeroed -> wait (correct). Stale-MAGIC passthrough (R10's
//     deadlock) is impossible.
// Everything else byte-identical to R16: coarse-filtered 256-bin hist
// (FG full-range >>15; BG m<2^16 >>8), per-block class totals, tree
// barrier B, completer select (parallel hist load + LDS scan), fanned
// CFLG wake, emit with boundary-bin candidate push, tree barrier D,
// completer fixup (exact rank on full keys), vmcnt(0) before arrivals.
// ===========================================================================

#define NUM_A 9
#define HW 65536
#define N_ANCH 589824
#define NG 64
#define CAPK 128u
#define NBINS 256
#define BG_TC 65536u                     // BG coarse filter threshold on m
#define CAND_CAP 2048

#define LAB_BG 0u
#define LAB_FG 1u
#define LAB_IGN 2u

#define NBLK 576

// workspace layout (u32 words)
#define OFF_HF    0                      // 256 fg hist (full range, >>15)
#define OFF_HB    256                    // 256 bg hist ([0,2^16), >>8)
#define OFF_TOTF  512                    // 32 x stride16 per-group fg totals
#define OFF_TOTB  1024                   // 32 x stride16 bg totals
#define OFF_SUBB  1536                   // 32 x stride16 barrier-B subs
#define OFF_ROOTB 2048                   // (pad 16)
#define OFF_SUBD  2064                   // 32 x stride16 barrier-D subs
#define OFF_ROOTD 2576                   // (pad 16)
#define OFF_SEL   2592                   // 10 used: {mode,bin,below,need,K}x2
#define OFF_CFLG  2608                   // 32 x stride16 wake flags
#define OFF_CNTF  3120                   // candidate counter fg (pad 16)
#define OFF_CNTB  3136                   // candidate counter bg (pad 16)
#define CTRL_WORDS 3152                  // zeroed by block 0 (AG stores)
#define OFF_ZFLG  CTRL_WORDS             // 3152: 32 x stride16, NOT zeroed
                                         //   by block 0; completer clears
#define OFF_CANDF (OFF_ZFLG + 32*16)     // 3664 (byte 14656, 8B aligned)
#define OFF_CANDB (OFF_CANDF + 2*CAND_CAP)   // 7760; end 11856 (~47 KB)

#define MAGIC_C 0x5CA1AB1Eu
#define MAGIC_Z 0x7A3F19C5u

__constant__ float BA[NUM_A][4] = {
  { -84.f,  -40.f,  99.f,  55.f}, {-176.f,  -88.f, 191.f, 103.f},
  {-360.f, -184.f, 375.f, 199.f}, { -56.f,  -56.f,  71.f,  71.f},
  {-120.f, -120.f, 135.f, 135.f}, {-248.f, -248.f, 263.f, 263.f},
  { -36.f,  -80.f,  51.f,  95.f}, { -80.f, -168.f,  95.f, 183.f},
  {-168.f, -344.f, 183.f, 359.f}};

__host__ __device__ static inline void tf2x32(uint32_t k0, uint32_t k1,
                                              uint32_t x0, uint32_t x1,
                                              uint32_t* o0, uint32_t* o1) {
  const uint32_t ks2 = k0 ^ k1 ^ 0x1BD11BDAu;
#define TF_R(r) { x0 += x1; x1 = (x1 << (r)) | (x1 >> (32 - (r))); x1 ^= x0; }
  x0 += k0; x1 += k1;
  TF_R(13) TF_R(15) TF_R(26) TF_R(6)
  x0 += k1;  x1 += ks2 + 1u;
  TF_R(17) TF_R(29) TF_R(16) TF_R(24)
  x0 += ks2; x1 += k0 + 2u;
  TF_R(13) TF_R(15) TF_R(26) TF_R(6)
  x0 += k0;  x1 += k1 + 3u;
  TF_R(17) TF_R(29) TF_R(16) TF_R(24)
  x0 += k1;  x1 += ks2 + 4u;
  TF_R(13) TF_R(15) TF_R(26) TF_R(6)
  x0 += ks2; x1 += k0 + 5u;
#undef TF_R
  *o0 = x0; *o1 = x1;
}

__device__ static inline uint32_t mant_of(uint32_t k0, uint32_t k1, uint32_t n) {
  uint32_t o0, o1;
  tf2x32(k0, k1, 0u, n, &o0, &o1);
  return (o0 ^ o1) >> 9;                 // 23-bit mantissa
}

// Max of fl(iw) over valid integer shifts [lo,hi] for one axis (concave,
// unimodal; max at clamped floor/ceil of continuous argmax endpoints).
__device__ static inline float axis_best(float blo, float bhi, float glo,
                                         float ghi, int lo, int hi) {
  #pragma clang fp contract(off)
  float t1 = (ghi - bhi) * 0.0625f;
  float t2 = (glo - blo) * 0.0625f;
  float tmin = fminf(t1, t2), tmax = fmaxf(t1, t2);
  int c1 = (int)floorf(tmin), c2 = (int)ceilf(tmax);
  int cand0 = lo, cand1 = hi;
  int cand2 = min(max(c1,     lo), hi);
  int cand3 = min(max(c1 + 1, lo), hi);
  int cand4 = min(max(c2 - 1, lo), hi);
  int cand5 = min(max(c2,     lo), hi);
  float best = -3.0e38f;
  int cands[6] = {cand0, cand1, cand2, cand3, cand4, cand5};
  #pragma unroll
  for (int i = 0; i < 6; i++) {
    float s = (float)(cands[i] << 4);
    float v = fminf(bhi + s, ghi) - fmaxf(blo + s, glo) + 1.0f;
    best = fmaxf(best, v);
  }
  return best;
}

#define AG_LOAD(p)      __hip_atomic_load((p), __ATOMIC_RELAXED, __HIP_MEMORY_SCOPE_AGENT)
#define AG_STORE(p, v)  __hip_atomic_store((p), (v), __ATOMIC_RELAXED, __HIP_MEMORY_SCOPE_AGENT)

__global__ __launch_bounds__(256) void k_one(const float* __restrict__ gt,
                                             const int* __restrict__ imw_p,
                                             const int* __restrict__ imh_p,
                                             float* __restrict__ out_lab,
                                             float* __restrict__ out_adj,
                                             float* __restrict__ out_wts,
                                             uint32_t* __restrict__ ws,
                                             uint32_t kf0, uint32_t kf1,
                                             uint32_t kb0, uint32_t kb1) {
  #pragma clang fp contract(off)
  __shared__ uint64_t scB[CAND_CAP];         // 16 KB; hist+scan view aliased
  uint32_t* sh = (uint32_t*)scB;             // [0..511] LDS hist, scan buf
  __shared__ float sg0[NG], sg1[NG], sg2[NG], sg3[NG], sga[NG], sgm[NG];
  __shared__ uint32_t sgmU[NG];
  __shared__ unsigned long long sMask[4];
  __shared__ int sAnyZero, sLastB, sLastD;
  __shared__ uint32_t sSel[10];
  __shared__ uint32_t sCF, sCB;
  int tid = threadIdx.x;
  int b = blockIdx.x;
  int a = b >> 6, hb = (b & 63) << 2;        // anchor type, rows hb..hb+3

  // ---- block 0: zero ctrl region (AGENT-scope stores -> performed at IF,
  // no dirty-L2 clobber), then publish fanned ZFLAG = MAGIC_Z ----
  if (b == 0) {
    for (int i = tid; i < CTRL_WORDS; i += 256) AG_STORE(&ws[i], 0u);
    asm volatile("s_waitcnt vmcnt(0)" ::: "memory");
    __syncthreads();                         // all zero-stores at IF
    if (tid < 32) AG_STORE(&ws[OFF_ZFLG + tid * 16], MAGIC_Z);
  }

  ((uint2*)sh)[tid] = make_uint2(0, 0);      // zero 512-word LDS hist
  if (tid == 0) { sAnyZero = 0; sCF = 0u; sCB = 0u; }
  if (tid < NG) {
    const float4 g4 = ((const float4*)gt)[tid];
    sg0[tid] = g4.x; sg1[tid] = g4.y; sg2[tid] = g4.z; sg3[tid] = g4.w;
    float gw = g4.z - g4.x + 1.0f, gh = g4.w - g4.y + 1.0f;
    sga[tid] = (gw > 0.0f && gh > 0.0f) ? gw * gh : 0.0f;
    sgmU[tid] = 0u;
  }
  __syncthreads();   // S1

  // ---- local analytic gmax (LDS atomicMax on float bits; IoU >= 0) ----
  {
    int imwi = imw_p[0], imhi = imh_p[0];
    for (int p = tid; p < NG * NUM_A; p += 256) {
      int g = p / NUM_A, q = p - g * NUM_A;
      float b0 = BA[q][0], b1 = BA[q][1], b2 = BA[q][2], b3 = BA[q][3];
      int ib0 = (int)b0, ib1 = (int)b1, ib2 = (int)b2, ib3 = (int)b3;
      int wlo = max(0, (-ib0 + 15) >> 4);
      int whi = min(255, (imwi - ib2 - 1) >> 4);
      int hlo = max(0, (-ib1 + 15) >> 4);
      int hhi = min(255, (imhi - ib3 - 1) >> 4);
      if (wlo > whi || hlo > hhi) continue;
      float iwb = axis_best(b0, b2, sg0[g], sg2[g], wlo, whi);
      float ihb = axis_best(b1, b3, sg1[g], sg3[g], hlo, hhi);
      float aw = b2 - b0 + 1.0f, ah = b3 - b1 + 1.0f;
      float aarea = aw * ah;
      float inter = (iwb > 0.0f && ihb > 0.0f) ? iwb * ihb : 0.0f;
      float den = aarea + sga[g] - inter;
      float o = inter / den;
      atomicMax(&sgmU[g], __float_as_uint(o));
    }
  }

  // per-wave y-mask
  {
    int wv = tid >> 6, g = tid & 63;
    float sy = (float)((hb + wv) << 4);
    float ihp = fminf(BA[a][3] + sy, sg3[g]) - fmaxf(BA[a][1] + sy, sg1[g]) + 1.0f;
    unsigned long long mk = __ballot(ihp > 0.0f);
    if (g == 0) sMask[wv] = mk;
  }
  __syncthreads();   // S2
  if (tid < NG) {
    uint32_t mm = sgmU[tid];
    sgm[tid] = __uint_as_float(mm);
    if (mm == 0u) atomicOr(&sAnyZero, 1);
  }
  __syncthreads();   // S3

  float BA0 = BA[a][0], BA1 = BA[a][1], BA2 = BA[a][2], BA3 = BA[a][3];
  float imw = (float)imw_p[0], imh = (float)imh_p[0];
  int w = tid;
  float sx = (float)(w << 4);
  float A0 = BA0 + sx, A2 = BA2 + sx;
  float aw = A2 - A0 + 1.0f;
  float A1v[4], A3v[4];
  #pragma unroll
  for (int r = 0; r < 4; r++) {
    float sy = (float)((hb + r) << 4);
    A1v[r] = BA1 + sy; A3v[r] = BA3 + sy;
  }
  float ah = A3v[0] - A1v[0] + 1.0f;
  float aarea = aw * ah;                   // exact ints -> bit-exact
  bool xv = (A0 >= 0.0f) && (A2 < imw);

  unsigned long long mk0 = sMask[0], mk1 = sMask[1],
                     mk2 = sMask[2], mk3 = sMask[3];
  unsigned long long uni = mk0 | mk1 | mk2 | mk3;
  float amaxv[4] = {0.f, 0.f, 0.f, 0.f};
  int bgv[4] = {0, 0, 0, 0};
  uint32_t afv = 0u;
  while (uni) {
    int g = __ffsll(uni) - 1;
    uni &= uni - 1;
    float iw = fminf(A2, sg2[g]) - fmaxf(A0, sg0[g]) + 1.0f;
    if (!__any(iw > 0.0f)) continue;
    if (iw > 0.0f) {
      float base = aarea + sga[g];
      float gy1 = sg1[g], gy2 = sg3[g], gm = sgm[g];
#define DO_ROW(r, mk)                                                     \
      if ((mk >> g) & 1ull) {                                             \
        float ih = fminf(A3v[r], gy2) - fmaxf(A1v[r], gy1) + 1.0f;        \
        float inter = iw * ih;                                            \
        float o = inter / (base - inter);                                 \
        if (o > amaxv[r]) { amaxv[r] = o; bgv[r] = g; }                   \
        if (o == gm) afv |= (1u << r);                                    \
      }
      DO_ROW(0, mk0) DO_ROW(1, mk1) DO_ROW(2, mk2) DO_ROW(3, mk3)
#undef DO_ROW
    }
  }

  bool anyZ = (sAnyZero != 0);
  uint32_t lm[4];
  uint32_t cfLoc = 0, cbLoc = 0;
  #pragma unroll
  for (int r = 0; r < 4; r++) {
    int hw = (hb + r) * 256 + w;
    bool valid = xv && (A1v[r] >= 0.0f) && (A3v[r] < imh);
    float amax = amaxv[r];
    bool anyfg = (((afv >> r) & 1u) || anyZ) && valid;
    uint32_t lab;
    if (!valid)                       lab = LAB_IGN;
    else if (anyfg || amax >= 0.7f)   lab = LAB_FG;
    else if (amax < 0.3f)             lab = LAB_BG;
    else                              lab = LAB_IGN;

    float adj0 = 0.f, adj1 = 0.f, adj2 = 0.f, adj3 = 0.f;
    if (valid) {
      int bg = bgv[r];
      float G0 = sg0[bg], G1 = sg1[bg], G2 = sg2[bg], G3 = sg3[bg];
      float ax = (A2 + A0) * 0.5f, ay = (A3v[r] + A1v[r]) * 0.5f;
      float gwm = G2 - G0 + 1.0f, ghm = G3 - G1 + 1.0f;
      float gx = (G2 + G0) * 0.5f, gy = (G3 + G1) * 0.5f;
      adj0 = (gx - ax) / aw;
      adj1 = (gy - ay) / ah;
      adj2 = logf(gwm / aw);
      adj3 = logf(ghm / ah);
    }
    int c4 = a * 4;
    out_adj[(c4 + 0) * HW + hw] = adj0;
    out_adj[(c4 + 1) * HW + hw] = adj1;
    out_adj[(c4 + 2) * HW + hw] = adj2;
    out_adj[(c4 + 3) * HW + hw] = adj3;

    uint32_t m = 0u;
    uint32_t n = (uint32_t)(hw * 9 + a);   // original anchor index (tie-break)
    if (lab != LAB_IGN) {
      uint32_t kk0 = (lab == LAB_FG) ? kf0 : kb0;
      uint32_t kk1 = (lab == LAB_FG) ? kf1 : kb1;
      m = mant_of(kk0, kk1, n);
      if (lab == LAB_FG) {
        cfLoc++;
        atomicAdd(&sh[m >> 15], 1u);                   // FG: full range >>15
      } else {
        cbLoc++;
        if (m < BG_TC) atomicAdd(&sh[NBINS + (m >> 8)], 1u);  // BG: coarse
      }
    }
    lm[r] = (lab << 24) | m;                 // stays in registers
  }
  if (cfLoc) atomicAdd(&sCF, cfLoc);
  if (cbLoc) atomicAdd(&sCB, cbLoc);
  __syncthreads();

  // ---- ZFLAG gate: ctrl region guaranteed zeroed past this point.
  // Lifecycle-safe: prev completer zeroed ZFLAG (or poison made it
  // garbage); only THIS run's block 0 can set MAGIC_Z, strictly after
  // its zero-stores are at the IF. Pre-satisfied in practice (~1us vs
  // ~10us of compute above). ----
  if (tid == 0) {
    while (AG_LOAD(&ws[OFF_ZFLG + (b & 31) * 16]) != MAGIC_Z)
      __builtin_amdgcn_s_sleep(2);
  }
  __syncthreads();

  // ---- global hist add (~9 atomics/block) + per-block totals ----
  for (int i = tid; i < 2 * NBINS; i += 256) {
    uint32_t v = sh[i];
    if (v) atomicAdd(&ws[OFF_HF + i], v);
  }
  if (tid == 0) {
    if (sCF) atomicAdd(&ws[OFF_TOTF + (b & 31) * 16], sCF);
    if (sCB) atomicAdd(&ws[OFF_TOTB + (b & 31) * 16], sCB);
  }
  asm volatile("s_waitcnt vmcnt(0)" ::: "memory");
  __syncthreads();

  // ---- barrier B: tree arrival; completer runs select ----
  if (tid == 0) {
    int last = 0;
    uint32_t v = atomicAdd(&ws[OFF_SUBB + (b & 31) * 16], 1u);
    if (v == 17u) {
      uint32_t r = atomicAdd(&ws[OFF_ROOTB], 1u);
      if (r == 31u) last = 1;
    }
    sLastB = last;
  }
  __syncthreads();
  if (sLastB) {
    // totals: 64 counters loaded in parallel, reduced via LDS
    __shared__ uint32_t sTots[64];
    if (tid < 32)       sTots[tid] = AG_LOAD(&ws[OFF_TOTF + tid * 16]);
    else if (tid < 64)  sTots[tid] = AG_LOAD(&ws[OFF_TOTB + (tid - 32) * 16]);
    __syncthreads();
    uint32_t totF = 0, totB = 0;
    if (tid == 0) {
      for (int i = 0; i < 32; i++) { totF += sTots[i]; totB += sTots[32 + i]; }
      sTots[0] = totF; sTots[1] = totB;
    }
    __syncthreads();
    totF = sTots[0]; totB = sTots[1];

    for (int cls = 0; cls < 2; cls++) {
      uint32_t* hist = ws + (cls ? OFF_HB : OFF_HF);
      uint32_t* sel = ws + OFF_SEL + cls * 5;
      uint32_t tot = cls ? totB : totF;
      uint32_t K = tot < CAPK ? tot : CAPK;
      uint32_t loc = AG_LOAD(&hist[tid]);      // 1 bin/thread, parallel
      sh[tid] = loc; __syncthreads();
      for (int off = 1; off < 256; off <<= 1) {
        uint32_t v = (tid >= off) ? sh[tid - off] : 0u;
        __syncthreads();
        sh[tid] += v;
        __syncthreads();
      }
      if (tid == 0) {
        uint32_t mode = (K == 0u) ? 0u : ((tot <= CAPK) ? 1u : 2u);
        AG_STORE(&sel[0], mode);
        AG_STORE(&sel[4], K);
        if (mode != 2u) {
          AG_STORE(&sel[1], 0xFFFFFFFFu); AG_STORE(&sel[2], 0u);
          AG_STORE(&sel[3], 0u);
        }
      }
      if (K > 0u && tot > CAPK) {
        uint32_t myC = sh[tid], pvC = (tid == 0) ? 0u : sh[tid - 1];
        if (myC >= K && pvC < K) {            // boundary bin = tid
          AG_STORE(&sel[1], (uint32_t)tid); AG_STORE(&sel[2], pvC);
          AG_STORE(&sel[3], K - pvC);
        }
      }
      __syncthreads();
    }
    asm volatile("s_waitcnt vmcnt(0)" ::: "memory");
    __syncthreads();                         // all SEL stores at IF
    if (tid < 32) AG_STORE(&ws[OFF_CFLG + tid * 16], MAGIC_C);
  }

  // ---- fanned-out wake: poll OWN sub-flag (<=18 pollers/address) ----
  if (tid == 0) {
    while (AG_LOAD(&ws[OFF_CFLG + (b & 31) * 16]) != MAGIC_C)
      __builtin_amdgcn_s_sleep(2);
  }
  __syncthreads();
  if (tid < 10) sSel[tid] = AG_LOAD(&ws[OFF_SEL + tid]);
  __syncthreads();
  uint32_t mF = sSel[0], bbF = sSel[1];
  uint32_t mB = sSel[5], bbB = sSel[6];
  uint32_t Kf = sSel[4], Kb = sSel[9];
  float inv = 1.0f / (float)(Kf + Kb);       // 1/num_ni

  // ---- emit; boundary-bin anchors deferred to completer fixup ----
  #pragma unroll
  for (int r = 0; r < 4; r++) {
    int hw = (hb + r) * 256 + w;
    uint32_t lab = lm[r] >> 24;
    uint32_t m = lm[r] & 0x7FFFFFu;
    uint32_t n = (uint32_t)(hw * 9 + a);
    float outv = 2.0f, wv = 0.0f;
    bool skip = false;                        // true -> fixup sole writer
    if (lab == LAB_FG) {
      if (mF == 1u) { outv = 1.0f; wv = inv; }
      else if (mF == 2u) {
        uint32_t bn = m >> 15;
        if (bn < bbF) { outv = 1.0f; wv = inv; }
        else if (bn == bbF) {
          uint32_t idx = atomicAdd(&ws[OFF_CNTF], 1u);
          if (idx < CAND_CAP) {
            AG_STORE((uint64_t*)(ws + OFF_CANDF) + idx,
                     ((uint64_t)m << 20) | (uint64_t)n);
            skip = true;
          }
        }
      }
    } else if (lab == LAB_BG) {
      if (mB == 1u) { outv = 0.0f; }
      else if (mB == 2u && m < BG_TC) {
        uint32_t bn = m >> 8;
        if (bn < bbB) { outv = 0.0f; }
        else if (bn == bbB) {
          uint32_t idx = atomicAdd(&ws[OFF_CNTB], 1u);
          if (idx < CAND_CAP) {
            AG_STORE((uint64_t*)(ws + OFF_CANDB) + idx,
                     ((uint64_t)m << 20) | (uint64_t)n);
            skip = true;
          }
        }
      }
    }
    if (!skip) {
      out_lab[a * HW + hw] = outv;
      int c4 = a * 4;
      out_wts[(c4 + 0) * HW + hw] = wv;
      out_wts[(c4 + 1) * HW + hw] = wv;
      out_wts[(c4 + 2) * HW + hw] = wv;
      out_wts[(c4 + 3) * HW + hw] = wv;
    }
  }

  asm volatile("s_waitcnt vmcnt(0)" ::: "memory");
  __syncthreads();

  // ---- barrier D: tree arrival; completer runs fixup; others exit ----
  if (tid == 0) {
    int last = 0;
    uint32_t v = atomicAdd(&ws[OFF_SUBD + (b & 31) * 16], 1u);
    if (v == 17u) {
      uint32_t r = atomicAdd(&ws[OFF_ROOTD], 1u);
      if (r == 31u) last = 1;
    }
    sLastD = last;
  }
  __syncthreads();
  if (sLastD) {
    for (int cls = 0; cls < 2; cls++) {
      uint32_t cnt = AG_LOAD(&ws[cls == 0 ? OFF_CNTF : OFF_CNTB]);
      uint32_t C = cnt < CAND_CAP ? cnt : CAND_CAP;
      uint32_t need = AG_LOAD(&ws[OFF_SEL + cls * 5 + 3]);
      const uint64_t* cand =
          (const uint64_t*)(ws + (cls == 0 ? OFF_CANDF : OFF_CANDB));
      for (uint32_t i = tid; i < C; i += 256)
        scB[i] = AG_LOAD(&cand[i]);           // parallel gather (R13 lesson)
      __syncthreads();
      for (uint32_t i = tid; i < C; i += 256) {
        uint64_t k = scB[i];
        uint32_t rr = 0;
        for (uint32_t j = 0; j < C; j++) rr += (scB[j] < k) ? 1u : 0u;
        bool kept = (rr < need);             // keys unique -> exactly need
        uint32_t nn = (uint32_t)(k & 0xFFFFFu);
        uint32_t aa = nn % 9u, hww = nn / 9u;
        uint32_t tt = aa * HW + hww;
        float lv = kept ? (cls == 0 ? 1.0f : 0.0f) : 2.0f;
        float wvv = (kept && cls == 0) ? inv : 0.0f;
        AG_STORE(&out_lab[tt], lv);
        #pragma unroll
        for (int j2 = 0; j2 < 4; j2++)
          AG_STORE(&out_wts[(aa * 4 + j2) * HW + hww], wvv);
      }
      __syncthreads();
    }
    // ---- lifecycle: clear ZFLAG for the next run (all blocks finished
    // their ZFLAG polls long before barrier D) ----
    if (tid < 32) AG_STORE(&ws[OFF_ZFLG + tid * 16], 0u);
  }
}

extern "C" void kernel_launch(void* const* d_in, const int* in_sizes, int n_in,
                              void* d_out, int out_size, void* d_ws,
                              size_t ws_size, hipStream_t stream) {
  const float* gt  = (const float*)d_in[1];
  const int*   imw = (const int*)d_in[2];
  const int*   imh = (const int*)d_in[3];
  float* out      = (float*)d_out;
  float* out_lab  = out;                   // 589824
  float* out_adj  = out + N_ANCH;          // 4*589824
  float* out_wts  = out + 5 * N_ANCH;      // 4*589824
  uint32_t* ws = (uint32_t*)d_ws;          // ~47 KB used

  uint32_t kf0, kf1, kb0, kb1;
  tf2x32(0u, 42u, 0u, 0u, &kf0, &kf1);
  tf2x32(0u, 42u, 0u, 1u, &kb0, &kb1);

  // SINGLE dispatch: ctrl zeroing folded into k_one (block 0 + ZFLAG gate,
  // lifecycle-safe against harness re-poison in either direction).
  // Residency by capacity: 576 blocks, ~18KB LDS -> 8 blocks/CU (2048
  // slots) >> 576; sole kernel on the stream -> all co-resident.
  hipLaunchKernelGGL(k_one, dim3(NBLK), dim3(256), 0, stream, gt, imw, imh,
                     out_lab, out_adj, out_wts, ws, kf0, kf1, kb0, kb1);
}